// Round 5
// baseline (596.908 us; speedup 1.0000x reference)
//
#include <hip/hip_runtime.h>

#define NGRAPH 2048

typedef __attribute__((ext_vector_type(8))) short bf16x8;
typedef __attribute__((ext_vector_type(4))) float f32x4;

__device__ inline unsigned short bf16_rne(float f) {
  union { float f; unsigned u; } c; c.f = f;
  unsigned u = c.u + 0x7fffu + ((c.u >> 16) & 1u);
  return (unsigned short)(u >> 16);
}
__device__ inline float bf16_to_f32(unsigned short h) {
  union { float f; unsigned u; } c; c.u = ((unsigned)h) << 16;
  return c.f;
}

// ================= CSR build =================
__global__ __launch_bounds__(256) void hist_deg(
    const int* __restrict__ dst, int* __restrict__ deg, int E)
{
  int e = blockIdx.x * 256 + threadIdx.x;
  if (e < E) atomicAdd(&deg[dst[e]], 1);
}

__global__ __launch_bounds__(256) void scan1(
    const int* __restrict__ deg, int* __restrict__ rowstart, int* __restrict__ bsum, int N)
{
  __shared__ int tmp[256];
  int i = blockIdx.x * 256 + threadIdx.x;
  int v = (i < N) ? deg[i] : 0;
  tmp[threadIdx.x] = v;
  __syncthreads();
#pragma unroll
  for (int off = 1; off < 256; off <<= 1) {
    int t = (threadIdx.x >= (unsigned)off) ? tmp[threadIdx.x - off] : 0;
    __syncthreads();
    tmp[threadIdx.x] += t;
    __syncthreads();
  }
  if (i < N) rowstart[i] = tmp[threadIdx.x] - v;
  if (threadIdx.x == 255) bsum[blockIdx.x] = tmp[255];
}

__global__ __launch_bounds__(1024) void scan2(
    int* __restrict__ bsum, int nb, int* __restrict__ rowstart, int N, int E)
{
  __shared__ int tmp[1024];
  int i = threadIdx.x;
  int v = (i < nb) ? bsum[i] : 0;
  tmp[i] = v;
  __syncthreads();
#pragma unroll
  for (int off = 1; off < 1024; off <<= 1) {
    int t = (i >= off) ? tmp[i - off] : 0;
    __syncthreads();
    tmp[i] += t;
    __syncthreads();
  }
  if (i < nb) bsum[i] = tmp[i] - v;
  if (i == 0) rowstart[N] = E;
}

__global__ __launch_bounds__(256) void scan3(
    int* __restrict__ rowstart, const int* __restrict__ bsum, int N)
{
  int i = blockIdx.x * 256 + threadIdx.x;
  if (i < N) rowstart[i] += bsum[blockIdx.x];
}

__global__ __launch_bounds__(256) void fill_eidx(
    const int* __restrict__ src, const int* __restrict__ dst,
    const int* __restrict__ rowstart, int* __restrict__ cursor,
    int* __restrict__ eidx, int E)
{
  int e = blockIdx.x * 256 + threadIdx.x;
  if (e >= E) return;
  int d = dst[e];
  int pos = rowstart[d] + atomicAdd(&cursor[d], 1);
  eidx[pos] = src[e];
}

// ================= gather7 (layer-1 aggregation, N x 7) =================
__global__ __launch_bounds__(256) void gather7(
    const float* __restrict__ x, const int* __restrict__ rowstart,
    const int* __restrict__ eidx, float* __restrict__ z1, int N)
{
  long t = (long)blockIdx.x * 256 + threadIdx.x;
  int v = (int)(t >> 3), j = (int)(t & 7);
  if (v >= N || j >= 7) return;
  float acc = x[(long)v * 7 + j];
  int e0 = rowstart[v], e1 = rowstart[v + 1];
  for (int e = e0; e < e1; ++e) {
    int s = eidx[e];
    acc += x[(long)s * 7 + j];
  }
  z1[(long)v * 7 + j] = acc;
}

// ================= weight prep: W[k][n] f32 -> bf16 hi/lo in MFMA fragment order =================
// chunk c = (t*4 + kc)*64 + lane; element e in [0,8): n = t*16 + (lane&15), k = kc*32 + (lane>>4)*8 + e
__global__ __launch_bounds__(256) void wprep(
    const float* __restrict__ W, unsigned short* __restrict__ hi, unsigned short* __restrict__ lo)
{
  int j = blockIdx.x * 256 + threadIdx.x;    // 0..16383
  int c = j >> 3, e = j & 7;
  int t = c >> 8, kc = (c >> 6) & 3, lane = c & 63;
  int n = t * 16 + (lane & 15);
  int k = kc * 32 + (lane >> 4) * 8 + e;
  float w = W[k * 128 + n];
  unsigned short h = bf16_rne(w);
  float r = w - bf16_to_f32(h);
  hi[j] = h;
  lo[j] = bf16_rne(r);
}

// helper: one split-precision GEMM pass over the 128x128 LDS tile (swizzled stride-128)
// each of 4 waves computes 32 rows x 128 cols; results left in acc[2][8] (C layout).
__device__ inline void mfma_pass(
    const float* __restrict__ zbuf,     // LDS, row r at zbuf[r*128 + ((c + (r&7)*4)&127)]
    const unsigned short* __restrict__ Whi, const unsigned short* __restrict__ Wlo,
    int rw, int m16, int quad, int lane, f32x4 acc[2][8])
{
#pragma unroll
  for (int kc = 0; kc < 4; ++kc) {
    int k0 = kc * 32 + quad * 8;
    bf16x8 ah[2], al[2];
#pragma unroll
    for (int rt = 0; rt < 2; ++rt) {
      int r = rw + rt * 16 + m16;
      int rot = (m16 & 7) * 4;
      const float* zrow = &zbuf[r * 128];
      float4 z0 = *(const float4*)&zrow[(k0 + rot) & 127];
      float4 z1 = *(const float4*)&zrow[(k0 + 4 + rot) & 127];
      float v[8] = {z0.x, z0.y, z0.z, z0.w, z1.x, z1.y, z1.z, z1.w};
#pragma unroll
      for (int j = 0; j < 8; ++j) {
        unsigned short h = bf16_rne(v[j]);
        ah[rt][j] = (short)h;
        al[rt][j] = (short)bf16_rne(v[j] - bf16_to_f32(h));
      }
    }
#pragma unroll
    for (int t = 0; t < 8; ++t) {
      int cb = ((t * 4 + kc) * 64 + lane) * 8;
      bf16x8 bh = *(const bf16x8*)&Whi[cb];
      bf16x8 bl = *(const bf16x8*)&Wlo[cb];
#pragma unroll
      for (int rt = 0; rt < 2; ++rt) {
        acc[rt][t] = __builtin_amdgcn_mfma_f32_16x16x32_bf16(ah[rt], bh, acc[rt][t], 0, 0, 0);
        acc[rt][t] = __builtin_amdgcn_mfma_f32_16x16x32_bf16(ah[rt], bl, acc[rt][t], 0, 0, 0);
        acc[rt][t] = __builtin_amdgcn_mfma_f32_16x16x32_bf16(al[rt], bh, acc[rt][t], 0, 0, 0);
      }
    }
  }
}

// ================= fused GIN layer (layers 2,3): gather + relu(z@W1+b1)@... =================
// Hout = relu( relu( (H + A*H) @ W1 + b1 ) @ W2 + b2 ), 128-row tile per block.
__global__ __launch_bounds__(256, 2) void fused_gin(
    const float* __restrict__ H, const int* __restrict__ rowstart,
    const int* __restrict__ eidx,
    const unsigned short* __restrict__ W1hi, const unsigned short* __restrict__ W1lo,
    const float* __restrict__ B1,
    const unsigned short* __restrict__ W2hi, const unsigned short* __restrict__ W2lo,
    const float* __restrict__ B2,
    float* __restrict__ Out, int M)
{
  __shared__ float zbuf[128 * 128];   // 64 KB, swizzled rows
  int tid = threadIdx.x;
  int rbase = blockIdx.x * 128;

  // ---- phase 1: gather 128 rows (z = self + neighbor sum) into zbuf ----
  {
    int rg = tid >> 5;              // 0..7
    int c = (tid & 31) * 4;
    int pc = (c + rg * 4) & 127;    // rot for row r: (r&7)*4 = rg*4
    const float* Hc = H + c;
#pragma unroll 2
    for (int it = 0; it < 16; ++it) {
      int r = it * 8 + rg;
      int v = rbase + r;
      int vc = (v < M) ? v : (M - 1);
      float4 a0 = *(const float4*)&Hc[(long)vc * 128];
      float4 a1 = {0.f,0.f,0.f,0.f}, a2 = {0.f,0.f,0.f,0.f}, a3 = {0.f,0.f,0.f,0.f};
      int e0 = rowstart[vc], e1 = rowstart[vc + 1];
      int e = e0;
      for (; e + 4 <= e1; e += 4) {
        int s0 = eidx[e], s1 = eidx[e + 1], s2 = eidx[e + 2], s3 = eidx[e + 3];
        float4 h0 = *(const float4*)&Hc[(long)s0 * 128];
        float4 h1 = *(const float4*)&Hc[(long)s1 * 128];
        float4 h2 = *(const float4*)&Hc[(long)s2 * 128];
        float4 h3 = *(const float4*)&Hc[(long)s3 * 128];
        a0.x += h0.x; a0.y += h0.y; a0.z += h0.z; a0.w += h0.w;
        a1.x += h1.x; a1.y += h1.y; a1.z += h1.z; a1.w += h1.w;
        a2.x += h2.x; a2.y += h2.y; a2.z += h2.z; a2.w += h2.w;
        a3.x += h3.x; a3.y += h3.y; a3.z += h3.z; a3.w += h3.w;
      }
      for (; e < e1; ++e) {
        int s = eidx[e];
        float4 h = *(const float4*)&Hc[(long)s * 128];
        a1.x += h.x; a1.y += h.y; a1.z += h.z; a1.w += h.w;
      }
      a0.x += a1.x + a2.x + a3.x;
      a0.y += a1.y + a2.y + a3.y;
      a0.z += a1.z + a2.z + a3.z;
      a0.w += a1.w + a2.w + a3.w;
      *(float4*)&zbuf[r * 128 + pc] = a0;
    }
  }
  __syncthreads();

  int lane = tid & 63;
  int wv = tid >> 6;
  int m16 = lane & 15;
  int quad = lane >> 4;
  int rw = wv * 32;

  // ---- phase 2: y = relu(z @ W1 + b1) ----
  f32x4 acc[2][8];
#pragma unroll
  for (int rt = 0; rt < 2; ++rt)
#pragma unroll
    for (int t = 0; t < 8; ++t) acc[rt][t] = (f32x4){0.f, 0.f, 0.f, 0.f};
  mfma_pass(zbuf, W1hi, W1lo, rw, m16, quad, lane, acc);

  float bias[8];
#pragma unroll
  for (int t = 0; t < 8; ++t) bias[t] = B1[t * 16 + m16];

  __syncthreads();   // all zbuf reads done before overwrite
#pragma unroll
  for (int rt = 0; rt < 2; ++rt) {
#pragma unroll
    for (int i = 0; i < 4; ++i) {
      int r = rw + rt * 16 + quad * 4 + i;
      int rot = (r & 7) * 4;
      float* yrow = &zbuf[r * 128];
#pragma unroll
      for (int t = 0; t < 8; ++t) {
        int col = t * 16 + m16;
        yrow[(col + rot) & 127] = fmaxf(acc[rt][t][i] + bias[t], 0.f);
      }
    }
  }
  __syncthreads();

  // ---- phase 3: Hout = relu(y @ W2 + b2) ----
#pragma unroll
  for (int rt = 0; rt < 2; ++rt)
#pragma unroll
    for (int t = 0; t < 8; ++t) acc[rt][t] = (f32x4){0.f, 0.f, 0.f, 0.f};
  mfma_pass(zbuf, W2hi, W2lo, rw, m16, quad, lane, acc);

#pragma unroll
  for (int t = 0; t < 8; ++t) bias[t] = B2[t * 16 + m16];

#pragma unroll
  for (int rt = 0; rt < 2; ++rt) {
#pragma unroll
    for (int i = 0; i < 4; ++i) {
      int r = rbase + rw + rt * 16 + quad * 4 + i;
      if (r < M) {
#pragma unroll
        for (int t = 0; t < 8; ++t) {
          float o = acc[rt][t][i] + bias[t];
          Out[(long)r * 128 + t * 16 + m16] = fmaxf(o, 0.f);
        }
      }
    }
  }
}

// ================= fused layer 1: y = relu(z1(Nx7) @ W1 + b1); Hout = relu(y @ W2 + b2) =================
__global__ __launch_bounds__(256, 2) void fused_l1(
    const float* __restrict__ Z1, const float* __restrict__ W1, const float* __restrict__ B1,
    const unsigned short* __restrict__ W2hi, const unsigned short* __restrict__ W2lo,
    const float* __restrict__ B2, float* __restrict__ Out, int M)
{
  __shared__ float ybuf[128 * 128];
  int tid = threadIdx.x;
  int rbase = blockIdx.x * 128;

  // ---- phase A: K=7 GEMM direct into LDS ----
  {
    int c = tid & 127;
    int rh0 = (tid >> 7) * 64;
    float w1r[7];
#pragma unroll
    for (int k = 0; k < 7; ++k) w1r[k] = W1[k * 128 + c];
    float b1 = B1[c];
#pragma unroll 4
    for (int rr = 0; rr < 64; ++rr) {
      int r = rh0 + rr;
      long vc = (rbase + r < M) ? (rbase + r) : (M - 1);
      const float* zp = &Z1[vc * 7];
      float a = b1;
#pragma unroll
      for (int k = 0; k < 7; ++k) a += zp[k] * w1r[k];
      ybuf[r * 128 + ((c + (r & 7) * 4) & 127)] = fmaxf(a, 0.f);
    }
  }
  __syncthreads();

  int lane = tid & 63;
  int wv = tid >> 6;
  int m16 = lane & 15;
  int quad = lane >> 4;
  int rw = wv * 32;

  f32x4 acc[2][8];
#pragma unroll
  for (int rt = 0; rt < 2; ++rt)
#pragma unroll
    for (int t = 0; t < 8; ++t) acc[rt][t] = (f32x4){0.f, 0.f, 0.f, 0.f};
  mfma_pass(ybuf, W2hi, W2lo, rw, m16, quad, lane, acc);

  float bias[8];
#pragma unroll
  for (int t = 0; t < 8; ++t) bias[t] = B2[t * 16 + m16];

#pragma unroll
  for (int rt = 0; rt < 2; ++rt) {
#pragma unroll
    for (int i = 0; i < 4; ++i) {
      int r = rbase + rw + rt * 16 + quad * 4 + i;
      if (r < M) {
#pragma unroll
        for (int t = 0; t < 8; ++t) {
          float o = acc[rt][t][i] + bias[t];
          Out[(long)r * 128 + t * 16 + m16] = fmaxf(o, 0.f);
        }
      }
    }
  }
}

// ================= fp32 GEMM for the small head (M=2048) =================
template <bool RELU>
__global__ __launch_bounds__(256) void gemm_k128(
    const float* __restrict__ Z,
    const float* __restrict__ W, const float* __restrict__ B,
    float* __restrict__ Out, int M)
{
  __shared__ float wlds[128 * 128];
  int tid = threadIdx.x;
  {
    const float4* Ws = (const float4*)W;
    float4* Wd = (float4*)wlds;
#pragma unroll
    for (int i = 0; i < 16; ++i) Wd[i * 256 + tid] = Ws[i * 256 + tid];
  }
  __syncthreads();

  int rg = tid >> 5;
  int c0 = (tid & 31) * 4;
  int rbase = blockIdx.x * 64 + rg * 8;

  int rcl[8];
#pragma unroll
  for (int i = 0; i < 8; ++i) {
    int r = rbase + i;
    rcl[i] = (r < M) ? r : (M - 1);
  }

  float acc[8][4];
#pragma unroll
  for (int i = 0; i < 8; ++i)
#pragma unroll
    for (int j = 0; j < 4; ++j) acc[i][j] = 0.f;

#pragma unroll 2
  for (int kc = 0; kc < 128; kc += 4) {
    float zv[8][4];
#pragma unroll
    for (int i = 0; i < 8; ++i) {
      float4 z = *(const float4*)&Z[(long)rcl[i] * 128 + kc];
      zv[i][0] = z.x; zv[i][1] = z.y; zv[i][2] = z.z; zv[i][3] = z.w;
    }
#pragma unroll
    for (int kk = 0; kk < 4; ++kk) {
      float4 w = *(const float4*)&wlds[(kc + kk) * 128 + c0];
#pragma unroll
      for (int i = 0; i < 8; ++i) {
        float z = zv[i][kk];
        acc[i][0] += z * w.x; acc[i][1] += z * w.y;
        acc[i][2] += z * w.z; acc[i][3] += z * w.w;
      }
    }
  }

  float4 b = *(const float4*)&B[c0];
#pragma unroll
  for (int i = 0; i < 8; ++i) {
    int r = rbase + i;
    if (r < M) {
      float4 o;
      o.x = acc[i][0] + b.x; o.y = acc[i][1] + b.y;
      o.z = acc[i][2] + b.z; o.w = acc[i][3] + b.w;
      if (RELU) {
        o.x = fmaxf(o.x, 0.f); o.y = fmaxf(o.y, 0.f);
        o.z = fmaxf(o.z, 0.f); o.w = fmaxf(o.w, 0.f);
      }
      *(float4*)&Out[(long)r * 128 + c0] = o;
    }
  }
}

// ================= pooling =================
template <bool DO_CNT>
__global__ __launch_bounds__(256) void pool128(
    const float* __restrict__ H, const int* __restrict__ batch,
    float* __restrict__ P, float* __restrict__ cnt, int Nn, int colOff)
{
  long t = (long)blockIdx.x * 256 + threadIdx.x;
  int cg = (int)(t & 31);
  int chunk = (int)(t >> 5);
  int i0 = chunk * 16;
  if (i0 >= Nn) return;
  int c = cg * 4;
  float4 acc = {0.f, 0.f, 0.f, 0.f};
  int curb = -1;
  float runc = 0.f;
  for (int ii = 0; ii < 16; ++ii) {
    int i = i0 + ii;
    if (i >= Nn) break;
    int b = batch[i];
    if (b != curb) {
      if (curb >= 0) {
        float* p = &P[(long)curb * 384 + colOff + c];
        atomicAdd(p + 0, acc.x); atomicAdd(p + 1, acc.y);
        atomicAdd(p + 2, acc.z); atomicAdd(p + 3, acc.w);
        if (DO_CNT && cg == 0) atomicAdd(&cnt[curb], runc);
      }
      acc.x = acc.y = acc.z = acc.w = 0.f;
      runc = 0.f;
      curb = b;
    }
    const float4 v = *(const float4*)&H[(long)i * 128 + c];
    acc.x += v.x; acc.y += v.y; acc.z += v.z; acc.w += v.w;
    runc += 1.f;
  }
  if (curb >= 0) {
    float* p = &P[(long)curb * 384 + colOff + c];
    atomicAdd(p + 0, acc.x); atomicAdd(p + 1, acc.y);
    atomicAdd(p + 2, acc.z); atomicAdd(p + 3, acc.w);
    if (DO_CNT && cg == 0) atomicAdd(&cnt[curb], runc);
  }
}

// ================= JK: G = P(2048x384) @ W(384x128) + cnt*B =================
__global__ __launch_bounds__(256) void jk_gemm(
    const float* __restrict__ P, const float* __restrict__ cnt,
    const float* __restrict__ W, const float* __restrict__ B,
    float* __restrict__ G)
{
  __shared__ float pl[768];
  int tid = threadIdx.x, blk = blockIdx.x;
  for (int o = tid; o < 768; o += 256) pl[o] = P[(long)blk * 768 + o];
  __syncthreads();
  int rr = tid >> 7;
  int col = tid & 127;
  int row = blk * 2 + rr;
  float acc = cnt[row] * B[col];
#pragma unroll 8
  for (int k = 0; k < 384; ++k)
    acc += pl[rr * 384 + k] * W[k * 128 + col];
  G[(long)row * 128 + col] = acc;
}

// ================= batch-norm stats =================
__global__ __launch_bounds__(256) void bn_stats(
    const float* __restrict__ ZC, const float* __restrict__ gma, const float* __restrict__ bta,
    float* __restrict__ scale, float* __restrict__ shift)
{
  int col = blockIdx.x;
  int tid = threadIdx.x;
  float s = 0.f, s2 = 0.f;
  for (int r = tid; r < NGRAPH; r += 256) {
    float v = ZC[(long)r * 128 + col];
    s += v; s2 += v * v;
  }
  for (int off = 32; off > 0; off >>= 1) {
    s += __shfl_down(s, off, 64);
    s2 += __shfl_down(s2, off, 64);
  }
  __shared__ float ls[4], ls2[4];
  int w = tid >> 6;
  if ((tid & 63) == 0) { ls[w] = s; ls2[w] = s2; }
  __syncthreads();
  if (tid == 0) {
    s = ls[0] + ls[1] + ls[2] + ls[3];
    s2 = ls2[0] + ls2[1] + ls2[2] + ls2[3];
    float mu = s * (1.f / NGRAPH);
    float var = s2 * (1.f / NGRAPH) - mu * mu;
    float rs = rsqrtf(var + 1e-5f);
    float sc = gma[col] * rs;
    scale[col] = sc;
    shift[col] = bta[col] - mu * sc;
  }
}

// ================= BN apply + relu + final [128x2] matmul =================
__global__ __launch_bounds__(256) void bn_final(
    const float* __restrict__ ZC, const float* __restrict__ scale, const float* __restrict__ shift,
    const float* __restrict__ W2, const float* __restrict__ B2, float* __restrict__ out)
{
  int g = blockIdx.x * 256 + threadIdx.x;
  if (g >= NGRAPH) return;
  float a0 = B2[0], a1 = B2[1];
#pragma unroll 4
  for (int h = 0; h < 128; ++h) {
    float zn = ZC[(long)g * 128 + h] * scale[h] + shift[h];
    zn = fmaxf(zn, 0.f);
    a0 += zn * W2[2 * h];
    a1 += zn * W2[2 * h + 1];
  }
  out[2 * g] = a0;
  out[2 * g + 1] = a1;
}

extern "C" void kernel_launch(void* const* d_in, const int* in_sizes, int n_in,
                              void* d_out, int out_size, void* d_ws, size_t ws_size,
                              hipStream_t stream)
{
  const float* x    = (const float*)d_in[0];
  const int*   ei   = (const int*)d_in[1];
  const int*   batch = (const int*)d_in[3];
  const float* g1w1 = (const float*)d_in[4];  const float* g1b1 = (const float*)d_in[5];
  const float* g1w2 = (const float*)d_in[6];  const float* g1b2 = (const float*)d_in[7];
  const float* g2w1 = (const float*)d_in[8];  const float* g2b1 = (const float*)d_in[9];
  const float* g2w2 = (const float*)d_in[10]; const float* g2b2 = (const float*)d_in[11];
  const float* g3w1 = (const float*)d_in[12]; const float* g3b1 = (const float*)d_in[13];
  const float* g3w2 = (const float*)d_in[14]; const float* g3b2 = (const float*)d_in[15];
  const float* jkw  = (const float*)d_in[16]; const float* jkb  = (const float*)d_in[17];
  const float* c1w  = (const float*)d_in[18]; const float* c1b  = (const float*)d_in[19];
  const float* bng  = (const float*)d_in[20]; const float* bnb  = (const float*)d_in[21];
  const float* c2w  = (const float*)d_in[22]; const float* c2b  = (const float*)d_in[23];

  const int N = in_sizes[3];
  const int E = in_sizes[1] / 2;
  const int* src = ei;
  const int* dst = ei + E;

  char* w = (char*)d_ws;
  auto alloc = [&](size_t bytes) {
    char* p = w;
    w += (bytes + 255) & ~(size_t)255;
    return p;
  };
  float* hA   = (float*)alloc((size_t)N * 128 * 4);
  float* hB   = (float*)alloc((size_t)N * 128 * 4);
  float* z1   = (float*)alloc((size_t)N * 7 * 4);
  float* P    = (float*)alloc((size_t)NGRAPH * 384 * 4);
  float* cnt  = (float*)alloc((size_t)NGRAPH * 4);
  float* gbuf = (float*)alloc((size_t)NGRAPH * 128 * 4);
  float* zc   = (float*)alloc((size_t)NGRAPH * 128 * 4);
  float* scl  = (float*)alloc(128 * 4);
  float* shf  = (float*)alloc(128 * 4);
  int* deg      = (int*)alloc((size_t)N * 4);
  int* cursor   = (int*)alloc((size_t)N * 4);
  int* rowstart = (int*)alloc((size_t)(N + 1) * 4);
  int* bsum     = (int*)alloc((size_t)1024 * 4);
  int* eidx     = (int*)alloc((size_t)E * 4);
  unsigned short* wtbuf = (unsigned short*)alloc((size_t)5 * 2 * 16384 * 2);

  unsigned short* WThi[5];
  unsigned short* WTlo[5];
  for (int m = 0; m < 5; ++m) {
    WThi[m] = wtbuf + (size_t)m * 2 * 16384;
    WTlo[m] = WThi[m] + 16384;
  }

  const int nb = (N + 255) / 256;
  const int eb = (E + 255) / 256;

  // ---- CSR build (reused by all three layers) ----
  hipMemsetAsync(deg, 0, (size_t)N * 4, stream);
  hipMemsetAsync(cursor, 0, (size_t)N * 4, stream);
  hist_deg<<<eb, 256, 0, stream>>>(dst, deg, E);
  scan1<<<nb, 256, 0, stream>>>(deg, rowstart, bsum, N);
  scan2<<<1, 1024, 0, stream>>>(bsum, nb, rowstart, N, E);
  scan3<<<nb, 256, 0, stream>>>(rowstart, bsum, N);
  fill_eidx<<<eb, 256, 0, stream>>>(src, dst, rowstart, cursor, eidx, E);

  // ---- weight prep (fragment-ordered bf16 hi/lo) ----
  wprep<<<64, 256, 0, stream>>>(g1w2, WThi[0], WTlo[0]);
  wprep<<<64, 256, 0, stream>>>(g2w1, WThi[1], WTlo[1]);
  wprep<<<64, 256, 0, stream>>>(g2w2, WThi[2], WTlo[2]);
  wprep<<<64, 256, 0, stream>>>(g3w1, WThi[3], WTlo[3]);
  wprep<<<64, 256, 0, stream>>>(g3w2, WThi[4], WTlo[4]);

  hipMemsetAsync(P, 0, (size_t)NGRAPH * 384 * 4, stream);
  hipMemsetAsync(cnt, 0, (size_t)NGRAPH * 4, stream);

  const int fBlocks = (N + 127) / 128;
  const int poolBlocks = (((N + 15) / 16) * 32 + 255) / 256;

  // ---- layer 1 ----
  gather7<<<(int)(((long)N * 8 + 255) / 256), 256, 0, stream>>>(x, rowstart, eidx, z1, N);
  fused_l1<<<fBlocks, 256, 0, stream>>>(z1, g1w1, g1b1, WThi[0], WTlo[0], g1b2, hA, N);
  pool128<true><<<poolBlocks, 256, 0, stream>>>(hA, batch, P, cnt, N, 0);

  // ---- layer 2 ----
  fused_gin<<<fBlocks, 256, 0, stream>>>(hA, rowstart, eidx,
      WThi[1], WTlo[1], g2b1, WThi[2], WTlo[2], g2b2, hB, N);
  pool128<false><<<poolBlocks, 256, 0, stream>>>(hB, batch, P, cnt, N, 128);

  // ---- layer 3 ----
  fused_gin<<<fBlocks, 256, 0, stream>>>(hB, rowstart, eidx,
      WThi[3], WTlo[3], g3b1, WThi[4], WTlo[4], g3b2, hA, N);
  pool128<false><<<poolBlocks, 256, 0, stream>>>(hA, batch, P, cnt, N, 256);

  // ---- head ----
  jk_gemm<<<NGRAPH / 2, 256, 0, stream>>>(P, cnt, jkw, jkb, gbuf);
  gemm_k128<false><<<(NGRAPH + 63) / 64, 256, 0, stream>>>(gbuf, c1w, c1b, zc, NGRAPH);
  bn_stats<<<128, 256, 0, stream>>>(zc, bng, bnb, scl, shf);
  bn_final<<<(NGRAPH + 255) / 256, 256, 0, stream>>>(zc, scl, shf, c2w, c2b, (float*)d_out);
}

// Round 6
// 543.041 us; speedup vs baseline: 1.0992x; 1.0992x over previous
//
#include <hip/hip_runtime.h>

#define NGRAPH 2048

typedef __attribute__((ext_vector_type(8))) short bf16x8;
typedef __attribute__((ext_vector_type(4))) float f32x4;

__device__ inline unsigned short bf16_rne(float f) {
  union { float f; unsigned u; } c; c.f = f;
  unsigned u = c.u + 0x7fffu + ((c.u >> 16) & 1u);
  return (unsigned short)(u >> 16);
}
__device__ inline float bf16_to_f32(unsigned short h) {
  union { float f; unsigned u; } c; c.u = ((unsigned)h) << 16;
  return c.f;
}

// ================= CSR build =================
__global__ __launch_bounds__(256) void hist_deg(
    const int* __restrict__ dst, int* __restrict__ deg, int E)
{
  int e = blockIdx.x * 256 + threadIdx.x;
  if (e < E) atomicAdd(&deg[dst[e]], 1);
}

__global__ __launch_bounds__(256) void scan1(
    const int* __restrict__ deg, int* __restrict__ rowstart, int* __restrict__ bsum, int N)
{
  __shared__ int tmp[256];
  int i = blockIdx.x * 256 + threadIdx.x;
  int v = (i < N) ? deg[i] : 0;
  tmp[threadIdx.x] = v;
  __syncthreads();
#pragma unroll
  for (int off = 1; off < 256; off <<= 1) {
    int t = (threadIdx.x >= (unsigned)off) ? tmp[threadIdx.x - off] : 0;
    __syncthreads();
    tmp[threadIdx.x] += t;
    __syncthreads();
  }
  if (i < N) rowstart[i] = tmp[threadIdx.x] - v;
  if (threadIdx.x == 255) bsum[blockIdx.x] = tmp[255];
}

__global__ __launch_bounds__(1024) void scan2(
    int* __restrict__ bsum, int nb, int* __restrict__ rowstart, int N, int E)
{
  __shared__ int tmp[1024];
  int i = threadIdx.x;
  int v = (i < nb) ? bsum[i] : 0;
  tmp[i] = v;
  __syncthreads();
#pragma unroll
  for (int off = 1; off < 1024; off <<= 1) {
    int t = (i >= off) ? tmp[i - off] : 0;
    __syncthreads();
    tmp[i] += t;
    __syncthreads();
  }
  if (i < nb) bsum[i] = tmp[i] - v;
  if (i == 0) rowstart[N] = E;
}

__global__ __launch_bounds__(256) void scan3(
    int* __restrict__ rowstart, const int* __restrict__ bsum, int N)
{
  int i = blockIdx.x * 256 + threadIdx.x;
  if (i < N) rowstart[i] += bsum[blockIdx.x];
}

__global__ __launch_bounds__(256) void fill_eidx(
    const int* __restrict__ src, const int* __restrict__ dst,
    const int* __restrict__ rowstart, int* __restrict__ cursor,
    int* __restrict__ eidx, int E)
{
  int e = blockIdx.x * 256 + threadIdx.x;
  if (e >= E) return;
  int d = dst[e];
  int pos = rowstart[d] + atomicAdd(&cursor[d], 1);
  eidx[pos] = src[e];
}

// ================= gather7 (layer-1 aggregation, N x 7) =================
__global__ __launch_bounds__(256) void gather7(
    const float* __restrict__ x, const int* __restrict__ rowstart,
    const int* __restrict__ eidx, float* __restrict__ z1, int N)
{
  long t = (long)blockIdx.x * 256 + threadIdx.x;
  int v = (int)(t >> 3), j = (int)(t & 7);
  if (v >= N || j >= 7) return;
  float acc = x[(long)v * 7 + j];
  int e0 = rowstart[v], e1 = rowstart[v + 1];
  for (int e = e0; e < e1; ++e) {
    int s = eidx[e];
    acc += x[(long)s * 7 + j];
  }
  z1[(long)v * 7 + j] = acc;
}

// ================= weight prep: 5 matrices, W[k][n] f32 -> bf16 hi/lo fragment order =================
struct WPs {
  const float* w[5];
  unsigned short* hi[5];
  unsigned short* lo[5];
};
__global__ __launch_bounds__(256) void wprep5(WPs p)
{
  int g = blockIdx.x * 256 + threadIdx.x;   // 0..5*16384-1
  int m = g >> 14;
  int j = g & 16383;
  int c = j >> 3, e = j & 7;
  int t = c >> 8, kc = (c >> 6) & 3, lane = c & 63;
  int n = t * 16 + (lane & 15);
  int k = kc * 32 + (lane >> 4) * 8 + e;
  float w = p.w[m][k * 128 + n];
  unsigned short h = bf16_rne(w);
  float r = w - bf16_to_f32(h);
  p.hi[m][j] = h;
  p.lo[m][j] = bf16_rne(r);
}

// ---- one split-precision GEMM pass over a 64x128 LDS tile; weights from global ----
// wave computes 16 rows (rw..rw+15) x 128 cols into acc[8]
__device__ inline void mfma_pass(
    const float* __restrict__ zbuf,
    const unsigned short* __restrict__ Whi, const unsigned short* __restrict__ Wlo,
    int rw, int m16, int quad, int lane, f32x4 acc[8])
{
  int rot = (m16 & 7) * 4;
  const float* zrow = &zbuf[(rw + m16) * 128];
#pragma unroll
  for (int kc = 0; kc < 4; ++kc) {
    int k0 = kc * 32 + quad * 8;
    float4 z0 = *(const float4*)&zrow[(k0 + rot) & 127];
    float4 z1 = *(const float4*)&zrow[(k0 + 4 + rot) & 127];
    float v[8] = {z0.x, z0.y, z0.z, z0.w, z1.x, z1.y, z1.z, z1.w};
    bf16x8 ah, al;
#pragma unroll
    for (int j = 0; j < 8; ++j) {
      unsigned short h = bf16_rne(v[j]);
      ah[j] = (short)h;
      al[j] = (short)bf16_rne(v[j] - bf16_to_f32(h));
    }
#pragma unroll
    for (int t = 0; t < 8; ++t) {
      long cb = ((t * 4 + kc) * 64 + lane) * 8;
      bf16x8 bh = *(const bf16x8*)&Whi[cb];
      bf16x8 bl = *(const bf16x8*)&Wlo[cb];
      acc[t] = __builtin_amdgcn_mfma_f32_16x16x32_bf16(ah, bh, acc[t], 0, 0, 0);
      acc[t] = __builtin_amdgcn_mfma_f32_16x16x32_bf16(ah, bl, acc[t], 0, 0, 0);
      acc[t] = __builtin_amdgcn_mfma_f32_16x16x32_bf16(al, bh, acc[t], 0, 0, 0);
    }
  }
}

// ================= fused GIN layer (layers 2,3), 64-row tile, 32KB LDS =================
__global__ __launch_bounds__(256, 5) void fused_gin(
    const float* __restrict__ H, const int* __restrict__ rowstart,
    const int* __restrict__ eidx,
    const unsigned short* __restrict__ W1hi, const unsigned short* __restrict__ W1lo,
    const float* __restrict__ B1,
    const unsigned short* __restrict__ W2hi, const unsigned short* __restrict__ W2lo,
    const float* __restrict__ B2,
    float* __restrict__ Out, int M)
{
  __shared__ float zbuf[64 * 128];   // 32 KB, rows swizzled by (r&7)*4
  int tid = threadIdx.x;
  int rbase = blockIdx.x * 64;

  // ---- phase 1: gather 64 rows (z = self + neighbor sum) ----
  {
    int rg = tid >> 5;              // 0..7
    int c = (tid & 31) * 4;
    int pc = (c + rg * 4) & 127;    // rot for row r: (r&7)*4 = rg*4
    const float* Hc = H + c;
#pragma unroll 2
    for (int it = 0; it < 8; ++it) {
      int r = it * 8 + rg;
      int v = rbase + r;
      int vc = (v < M) ? v : (M - 1);
      float4 a0 = *(const float4*)&Hc[(long)vc * 128];
      float4 a1 = {0.f,0.f,0.f,0.f}, a2 = {0.f,0.f,0.f,0.f}, a3 = {0.f,0.f,0.f,0.f};
      int e0 = rowstart[vc], e1 = rowstart[vc + 1];
      int e = e0;
      for (; e + 4 <= e1; e += 4) {
        int s0 = eidx[e], s1 = eidx[e + 1], s2 = eidx[e + 2], s3 = eidx[e + 3];
        float4 h0 = *(const float4*)&Hc[(long)s0 * 128];
        float4 h1 = *(const float4*)&Hc[(long)s1 * 128];
        float4 h2 = *(const float4*)&Hc[(long)s2 * 128];
        float4 h3 = *(const float4*)&Hc[(long)s3 * 128];
        a0.x += h0.x; a0.y += h0.y; a0.z += h0.z; a0.w += h0.w;
        a1.x += h1.x; a1.y += h1.y; a1.z += h1.z; a1.w += h1.w;
        a2.x += h2.x; a2.y += h2.y; a2.z += h2.z; a2.w += h2.w;
        a3.x += h3.x; a3.y += h3.y; a3.z += h3.z; a3.w += h3.w;
      }
      for (; e < e1; ++e) {
        int s = eidx[e];
        float4 h = *(const float4*)&Hc[(long)s * 128];
        a1.x += h.x; a1.y += h.y; a1.z += h.z; a1.w += h.w;
      }
      a0.x += a1.x + a2.x + a3.x;
      a0.y += a1.y + a2.y + a3.y;
      a0.z += a1.z + a2.z + a3.z;
      a0.w += a1.w + a2.w + a3.w;
      *(float4*)&zbuf[r * 128 + pc] = a0;
    }
  }
  __syncthreads();

  int lane = tid & 63;
  int wv = tid >> 6;
  int m16 = lane & 15;
  int quad = lane >> 4;
  int rw = wv * 16;

  // ---- phase 2: y = relu(z @ W1 + b1) ----
  f32x4 acc[8];
#pragma unroll
  for (int t = 0; t < 8; ++t) acc[t] = (f32x4){0.f, 0.f, 0.f, 0.f};
  mfma_pass(zbuf, W1hi, W1lo, rw, m16, quad, lane, acc);

  float bias[8];
#pragma unroll
  for (int t = 0; t < 8; ++t) bias[t] = B1[t * 16 + m16];

  __syncthreads();   // all zbuf reads done before overwrite
#pragma unroll
  for (int i = 0; i < 4; ++i) {
    int r = rw + quad * 4 + i;
    int rot = (r & 7) * 4;
    float* yrow = &zbuf[r * 128];
#pragma unroll
    for (int t = 0; t < 8; ++t) {
      int col = t * 16 + m16;
      yrow[(col + rot) & 127] = fmaxf(acc[t][i] + bias[t], 0.f);
    }
  }
  __syncthreads();

  // ---- phase 3: Hout = relu(y @ W2 + b2) ----
#pragma unroll
  for (int t = 0; t < 8; ++t) acc[t] = (f32x4){0.f, 0.f, 0.f, 0.f};
  mfma_pass(zbuf, W2hi, W2lo, rw, m16, quad, lane, acc);

#pragma unroll
  for (int t = 0; t < 8; ++t) bias[t] = B2[t * 16 + m16];

#pragma unroll
  for (int i = 0; i < 4; ++i) {
    int r = rbase + rw + quad * 4 + i;
    if (r < M) {
#pragma unroll
      for (int t = 0; t < 8; ++t) {
        float o = acc[t][i] + bias[t];
        Out[(long)r * 128 + t * 16 + m16] = fmaxf(o, 0.f);
      }
    }
  }
}

// ================= fused layer 1: y = relu(z1@W1+b1) in LDS; Hout = relu(y@W2+b2) =================
__global__ __launch_bounds__(256, 5) void fused_l1(
    const float* __restrict__ Z1, const float* __restrict__ W1, const float* __restrict__ B1,
    const unsigned short* __restrict__ W2hi, const unsigned short* __restrict__ W2lo,
    const float* __restrict__ B2, float* __restrict__ Out, int M)
{
  __shared__ float ybuf[64 * 128];
  int tid = threadIdx.x;
  int rbase = blockIdx.x * 64;

  // ---- phase A: K=7 GEMM direct into LDS ----
  {
    int c = tid & 127;
    int rh0 = (tid >> 7) * 32;
    float w1r[7];
#pragma unroll
    for (int k = 0; k < 7; ++k) w1r[k] = W1[k * 128 + c];
    float b1 = B1[c];
#pragma unroll 4
    for (int rr = 0; rr < 32; ++rr) {
      int r = rh0 + rr;
      long vc = (rbase + r < M) ? (rbase + r) : (M - 1);
      const float* zp = &Z1[vc * 7];
      float a = b1;
#pragma unroll
      for (int k = 0; k < 7; ++k) a += zp[k] * w1r[k];
      ybuf[r * 128 + ((c + (r & 7) * 4) & 127)] = fmaxf(a, 0.f);
    }
  }
  __syncthreads();

  int lane = tid & 63;
  int wv = tid >> 6;
  int m16 = lane & 15;
  int quad = lane >> 4;
  int rw = wv * 16;

  f32x4 acc[8];
#pragma unroll
  for (int t = 0; t < 8; ++t) acc[t] = (f32x4){0.f, 0.f, 0.f, 0.f};
  mfma_pass(ybuf, W2hi, W2lo, rw, m16, quad, lane, acc);

  float bias[8];
#pragma unroll
  for (int t = 0; t < 8; ++t) bias[t] = B2[t * 16 + m16];

#pragma unroll
  for (int i = 0; i < 4; ++i) {
    int r = rbase + rw + quad * 4 + i;
    if (r < M) {
#pragma unroll
      for (int t = 0; t < 8; ++t) {
        float o = acc[t][i] + bias[t];
        Out[(long)r * 128 + t * 16 + m16] = fmaxf(o, 0.f);
      }
    }
  }
}

// ================= fp32 GEMM for the small head (M=2048) =================
template <bool RELU>
__global__ __launch_bounds__(256) void gemm_k128(
    const float* __restrict__ Z,
    const float* __restrict__ W, const float* __restrict__ B,
    float* __restrict__ Out, int M)
{
  __shared__ float wlds[128 * 128];
  int tid = threadIdx.x;
  {
    const float4* Ws = (const float4*)W;
    float4* Wd = (float4*)wlds;
#pragma unroll
    for (int i = 0; i < 16; ++i) Wd[i * 256 + tid] = Ws[i * 256 + tid];
  }
  __syncthreads();

  int rg = tid >> 5;
  int c0 = (tid & 31) * 4;
  int rbase = blockIdx.x * 64 + rg * 8;

  int rcl[8];
#pragma unroll
  for (int i = 0; i < 8; ++i) {
    int r = rbase + i;
    rcl[i] = (r < M) ? r : (M - 1);
  }

  float acc[8][4];
#pragma unroll
  for (int i = 0; i < 8; ++i)
#pragma unroll
    for (int j = 0; j < 4; ++j) acc[i][j] = 0.f;

#pragma unroll 2
  for (int kc = 0; kc < 128; kc += 4) {
    float zv[8][4];
#pragma unroll
    for (int i = 0; i < 8; ++i) {
      float4 z = *(const float4*)&Z[(long)rcl[i] * 128 + kc];
      zv[i][0] = z.x; zv[i][1] = z.y; zv[i][2] = z.z; zv[i][3] = z.w;
    }
#pragma unroll
    for (int kk = 0; kk < 4; ++kk) {
      float4 w = *(const float4*)&wlds[(kc + kk) * 128 + c0];
#pragma unroll
      for (int i = 0; i < 8; ++i) {
        float z = zv[i][kk];
        acc[i][0] += z * w.x; acc[i][1] += z * w.y;
        acc[i][2] += z * w.z; acc[i][3] += z * w.w;
      }
    }
  }

  float4 b = *(const float4*)&B[c0];
#pragma unroll
  for (int i = 0; i < 8; ++i) {
    int r = rbase + i;
    if (r < M) {
      float4 o;
      o.x = acc[i][0] + b.x; o.y = acc[i][1] + b.y;
      o.z = acc[i][2] + b.z; o.w = acc[i][3] + b.w;
      if (RELU) {
        o.x = fmaxf(o.x, 0.f); o.y = fmaxf(o.y, 0.f);
        o.z = fmaxf(o.z, 0.f); o.w = fmaxf(o.w, 0.f);
      }
      *(float4*)&Out[(long)r * 128 + c0] = o;
    }
  }
}

// ================= pooling =================
template <bool DO_CNT>
__global__ __launch_bounds__(256) void pool128(
    const float* __restrict__ H, const int* __restrict__ batch,
    float* __restrict__ P, float* __restrict__ cnt, int Nn, int colOff)
{
  long t = (long)blockIdx.x * 256 + threadIdx.x;
  int cg = (int)(t & 31);
  int chunk = (int)(t >> 5);
  int i0 = chunk * 16;
  if (i0 >= Nn) return;
  int c = cg * 4;
  float4 acc = {0.f, 0.f, 0.f, 0.f};
  int curb = -1;
  float runc = 0.f;
  for (int ii = 0; ii < 16; ++ii) {
    int i = i0 + ii;
    if (i >= Nn) break;
    int b = batch[i];
    if (b != curb) {
      if (curb >= 0) {
        float* p = &P[(long)curb * 384 + colOff + c];
        atomicAdd(p + 0, acc.x); atomicAdd(p + 1, acc.y);
        atomicAdd(p + 2, acc.z); atomicAdd(p + 3, acc.w);
        if (DO_CNT && cg == 0) atomicAdd(&cnt[curb], runc);
      }
      acc.x = acc.y = acc.z = acc.w = 0.f;
      runc = 0.f;
      curb = b;
    }
    const float4 v = *(const float4*)&H[(long)i * 128 + c];
    acc.x += v.x; acc.y += v.y; acc.z += v.z; acc.w += v.w;
    runc += 1.f;
  }
  if (curb >= 0) {
    float* p = &P[(long)curb * 384 + colOff + c];
    atomicAdd(p + 0, acc.x); atomicAdd(p + 1, acc.y);
    atomicAdd(p + 2, acc.z); atomicAdd(p + 3, acc.w);
    if (DO_CNT && cg == 0) atomicAdd(&cnt[curb], runc);
  }
}

// ================= JK: G = P(2048x384) @ W(384x128) + cnt*B =================
__global__ __launch_bounds__(256) void jk_gemm(
    const float* __restrict__ P, const float* __restrict__ cnt,
    const float* __restrict__ W, const float* __restrict__ B,
    float* __restrict__ G)
{
  __shared__ float pl[768];
  int tid = threadIdx.x, blk = blockIdx.x;
  for (int o = tid; o < 768; o += 256) pl[o] = P[(long)blk * 768 + o];
  __syncthreads();
  int rr = tid >> 7;
  int col = tid & 127;
  int row = blk * 2 + rr;
  float acc = cnt[row] * B[col];
#pragma unroll 8
  for (int k = 0; k < 384; ++k)
    acc += pl[rr * 384 + k] * W[k * 128 + col];
  G[(long)row * 128 + col] = acc;
}

// ================= batch-norm stats =================
__global__ __launch_bounds__(256) void bn_stats(
    const float* __restrict__ ZC, const float* __restrict__ gma, const float* __restrict__ bta,
    float* __restrict__ scale, float* __restrict__ shift)
{
  int col = blockIdx.x;
  int tid = threadIdx.x;
  float s = 0.f, s2 = 0.f;
  for (int r = tid; r < NGRAPH; r += 256) {
    float v = ZC[(long)r * 128 + col];
    s += v; s2 += v * v;
  }
  for (int off = 32; off > 0; off >>= 1) {
    s += __shfl_down(s, off, 64);
    s2 += __shfl_down(s2, off, 64);
  }
  __shared__ float ls[4], ls2[4];
  int w = tid >> 6;
  if ((tid & 63) == 0) { ls[w] = s; ls2[w] = s2; }
  __syncthreads();
  if (tid == 0) {
    s = ls[0] + ls[1] + ls[2] + ls[3];
    s2 = ls2[0] + ls2[1] + ls2[2] + ls2[3];
    float mu = s * (1.f / NGRAPH);
    float var = s2 * (1.f / NGRAPH) - mu * mu;
    float rs = rsqrtf(var + 1e-5f);
    float sc = gma[col] * rs;
    scale[col] = sc;
    shift[col] = bta[col] - mu * sc;
  }
}

// ================= BN apply + relu + final [128x2] matmul =================
__global__ __launch_bounds__(256) void bn_final(
    const float* __restrict__ ZC, const float* __restrict__ scale, const float* __restrict__ shift,
    const float* __restrict__ W2, const float* __restrict__ B2, float* __restrict__ out)
{
  int g = blockIdx.x * 256 + threadIdx.x;
  if (g >= NGRAPH) return;
  float a0 = B2[0], a1 = B2[1];
#pragma unroll 4
  for (int h = 0; h < 128; ++h) {
    float zn = ZC[(long)g * 128 + h] * scale[h] + shift[h];
    zn = fmaxf(zn, 0.f);
    a0 += zn * W2[2 * h];
    a1 += zn * W2[2 * h + 1];
  }
  out[2 * g] = a0;
  out[2 * g + 1] = a1;
}

extern "C" void kernel_launch(void* const* d_in, const int* in_sizes, int n_in,
                              void* d_out, int out_size, void* d_ws, size_t ws_size,
                              hipStream_t stream)
{
  const float* x    = (const float*)d_in[0];
  const int*   ei   = (const int*)d_in[1];
  const int*   batch = (const int*)d_in[3];
  const float* g1w1 = (const float*)d_in[4];  const float* g1b1 = (const float*)d_in[5];
  const float* g1w2 = (const float*)d_in[6];  const float* g1b2 = (const float*)d_in[7];
  const float* g2w1 = (const float*)d_in[8];  const float* g2b1 = (const float*)d_in[9];
  const float* g2w2 = (const float*)d_in[10]; const float* g2b2 = (const float*)d_in[11];
  const float* g3w1 = (const float*)d_in[12]; const float* g3b1 = (const float*)d_in[13];
  const float* g3w2 = (const float*)d_in[14]; const float* g3b2 = (const float*)d_in[15];
  const float* jkw  = (const float*)d_in[16]; const float* jkb  = (const float*)d_in[17];
  const float* c1w  = (const float*)d_in[18]; const float* c1b  = (const float*)d_in[19];
  const float* bng  = (const float*)d_in[20]; const float* bnb  = (const float*)d_in[21];
  const float* c2w  = (const float*)d_in[22]; const float* c2b  = (const float*)d_in[23];

  const int N = in_sizes[3];
  const int E = in_sizes[1] / 2;
  const int* src = ei;
  const int* dst = ei + E;

  char* w = (char*)d_ws;
  auto alloc = [&](size_t bytes) {
    char* p = w;
    w += (bytes + 255) & ~(size_t)255;
    return p;
  };
  float* hA   = (float*)alloc((size_t)N * 128 * 4);
  float* hB   = (float*)alloc((size_t)N * 128 * 4);
  float* z1   = (float*)alloc((size_t)N * 7 * 4);
  float* P    = (float*)alloc((size_t)NGRAPH * 384 * 4);
  float* cnt  = (float*)alloc((size_t)NGRAPH * 4);
  float* gbuf = (float*)alloc((size_t)NGRAPH * 128 * 4);
  float* zc   = (float*)alloc((size_t)NGRAPH * 128 * 4);
  float* scl  = (float*)alloc(128 * 4);
  float* shf  = (float*)alloc(128 * 4);
  int* deg      = (int*)alloc((size_t)N * 4);
  int* cursor   = (int*)alloc((size_t)N * 4);
  int* rowstart = (int*)alloc((size_t)(N + 1) * 4);
  int* bsum     = (int*)alloc((size_t)1024 * 4);
  int* eidx     = (int*)alloc((size_t)E * 4);
  unsigned short* wtbuf = (unsigned short*)alloc((size_t)5 * 2 * 16384 * 2);

  unsigned short* WThi[5];
  unsigned short* WTlo[5];
  for (int m = 0; m < 5; ++m) {
    WThi[m] = wtbuf + (size_t)m * 2 * 16384;
    WTlo[m] = WThi[m] + 16384;
  }

  const int nb = (N + 255) / 256;
  const int eb = (E + 255) / 256;

  // ---- CSR build (reused by all three layers) ----
  hipMemsetAsync(deg, 0, (size_t)N * 4, stream);
  hipMemsetAsync(cursor, 0, (size_t)N * 4, stream);
  hist_deg<<<eb, 256, 0, stream>>>(dst, deg, E);
  scan1<<<nb, 256, 0, stream>>>(deg, rowstart, bsum, N);
  scan2<<<1, 1024, 0, stream>>>(bsum, nb, rowstart, N, E);
  scan3<<<nb, 256, 0, stream>>>(rowstart, bsum, N);
  fill_eidx<<<eb, 256, 0, stream>>>(src, dst, rowstart, cursor, eidx, E);

  // ---- weight prep (fragment-ordered bf16 hi/lo), one launch ----
  {
    WPs p;
    p.w[0] = g1w2; p.w[1] = g2w1; p.w[2] = g2w2; p.w[3] = g3w1; p.w[4] = g3w2;
    for (int m = 0; m < 5; ++m) { p.hi[m] = WThi[m]; p.lo[m] = WTlo[m]; }
    wprep5<<<320, 256, 0, stream>>>(p);
  }

  hipMemsetAsync(P, 0, (size_t)NGRAPH * 384 * 4, stream);
  hipMemsetAsync(cnt, 0, (size_t)NGRAPH * 4, stream);

  const int fBlocks = (N + 63) / 64;
  const int poolBlocks = (((N + 15) / 16) * 32 + 255) / 256;

  // ---- layer 1 ----
  gather7<<<(int)(((long)N * 8 + 255) / 256), 256, 0, stream>>>(x, rowstart, eidx, z1, N);
  fused_l1<<<fBlocks, 256, 0, stream>>>(z1, g1w1, g1b1, WThi[0], WTlo[0], g1b2, hA, N);
  pool128<true><<<poolBlocks, 256, 0, stream>>>(hA, batch, P, cnt, N, 0);

  // ---- layer 2 ----
  fused_gin<<<fBlocks, 256, 0, stream>>>(hA, rowstart, eidx,
      WThi[1], WTlo[1], g2b1, WThi[2], WTlo[2], g2b2, hB, N);
  pool128<false><<<poolBlocks, 256, 0, stream>>>(hB, batch, P, cnt, N, 128);

  // ---- layer 3 ----
  fused_gin<<<fBlocks, 256, 0, stream>>>(hB, rowstart, eidx,
      WThi[3], WTlo[3], g3b1, WThi[4], WTlo[4], g3b2, hA, N);
  pool128<false><<<poolBlocks, 256, 0, stream>>>(hA, batch, P, cnt, N, 256);

  // ---- head ----
  jk_gemm<<<NGRAPH / 2, 256, 0, stream>>>(P, cnt, jkw, jkb, gbuf);
  gemm_k128<false><<<(NGRAPH + 63) / 64, 256, 0, stream>>>(gbuf, c1w, c1b, zc, NGRAPH);
  bn_stats<<<128, 256, 0, stream>>>(zc, bng, bnb, scl, shf);
  bn_final<<<(NGRAPH + 255) / 256, 256, 0, stream>>>(zc, scl, shf, c2w, c2b, (float*)d_out);
}

// Round 7
// 523.917 us; speedup vs baseline: 1.1393x; 1.0365x over previous
//
#include <hip/hip_runtime.h>

#define NGRAPH 2048

typedef __attribute__((ext_vector_type(8))) short bf16x8;
typedef __attribute__((ext_vector_type(4))) float f32x4;
typedef __attribute__((ext_vector_type(4))) _Float16 h16x4;

__device__ inline unsigned short bf16_rne(float f) {
  union { float f; unsigned u; } c; c.f = f;
  unsigned u = c.u + 0x7fffu + ((c.u >> 16) & 1u);
  return (unsigned short)(u >> 16);
}
__device__ inline float bf16_to_f32(unsigned short h) {
  union { float f; unsigned u; } c; c.u = ((unsigned)h) << 16;
  return c.f;
}

// ================= CSR build =================
__global__ __launch_bounds__(256) void hist_deg(
    const int* __restrict__ dst, int* __restrict__ deg, int E)
{
  int e = blockIdx.x * 256 + threadIdx.x;
  if (e < E) atomicAdd(&deg[dst[e]], 1);
}

__global__ __launch_bounds__(256) void scan1(
    const int* __restrict__ deg, int* __restrict__ rowstart, int* __restrict__ bsum, int N)
{
  __shared__ int tmp[256];
  int i = blockIdx.x * 256 + threadIdx.x;
  int v = (i < N) ? deg[i] : 0;
  tmp[threadIdx.x] = v;
  __syncthreads();
#pragma unroll
  for (int off = 1; off < 256; off <<= 1) {
    int t = (threadIdx.x >= (unsigned)off) ? tmp[threadIdx.x - off] : 0;
    __syncthreads();
    tmp[threadIdx.x] += t;
    __syncthreads();
  }
  if (i < N) rowstart[i] = tmp[threadIdx.x] - v;
  if (threadIdx.x == 255) bsum[blockIdx.x] = tmp[255];
}

__global__ __launch_bounds__(1024) void scan2(
    int* __restrict__ bsum, int nb, int* __restrict__ rowstart, int N, int E)
{
  __shared__ int tmp[1024];
  int i = threadIdx.x;
  int v = (i < nb) ? bsum[i] : 0;
  tmp[i] = v;
  __syncthreads();
#pragma unroll
  for (int off = 1; off < 1024; off <<= 1) {
    int t = (i >= off) ? tmp[i - off] : 0;
    __syncthreads();
    tmp[i] += t;
    __syncthreads();
  }
  if (i < nb) bsum[i] = tmp[i] - v;
  if (i == 0) rowstart[N] = E;
}

__global__ __launch_bounds__(256) void scan3(
    int* __restrict__ rowstart, const int* __restrict__ bsum, int N)
{
  int i = blockIdx.x * 256 + threadIdx.x;
  if (i < N) rowstart[i] += bsum[blockIdx.x];
}

__global__ __launch_bounds__(256) void fill_eidx(
    const int* __restrict__ src, const int* __restrict__ dst,
    const int* __restrict__ rowstart, int* __restrict__ cursor,
    int* __restrict__ eidx, int E)
{
  int e = blockIdx.x * 256 + threadIdx.x;
  if (e >= E) return;
  int d = dst[e];
  int pos = rowstart[d] + atomicAdd(&cursor[d], 1);
  eidx[pos] = src[e];
}

// ================= gather7 (layer-1 aggregation, N x 7, fp32) =================
__global__ __launch_bounds__(256) void gather7(
    const float* __restrict__ x, const int* __restrict__ rowstart,
    const int* __restrict__ eidx, float* __restrict__ z1, int N)
{
  long t = (long)blockIdx.x * 256 + threadIdx.x;
  int v = (int)(t >> 3), j = (int)(t & 7);
  if (v >= N || j >= 7) return;
  float acc = x[(long)v * 7 + j];
  int e0 = rowstart[v], e1 = rowstart[v + 1];
  for (int e = e0; e < e1; ++e) {
    int s = eidx[e];
    acc += x[(long)s * 7 + j];
  }
  z1[(long)v * 7 + j] = acc;
}

// ================= weight prep: 5 matrices, W[k][n] f32 -> bf16 hi/lo fragment order =================
struct WPs {
  const float* w[5];
  unsigned short* hi[5];
  unsigned short* lo[5];
};
__global__ __launch_bounds__(256) void wprep5(WPs p)
{
  int g = blockIdx.x * 256 + threadIdx.x;   // 0..5*16384-1
  int m = g >> 14;
  int j = g & 16383;
  int c = j >> 3, e = j & 7;
  int t = c >> 8, kc = (c >> 6) & 3, lane = c & 63;
  int n = t * 16 + (lane & 15);
  int k = kc * 32 + (lane >> 4) * 8 + e;
  float w = p.w[m][k * 128 + n];
  unsigned short h = bf16_rne(w);
  float r = w - bf16_to_f32(h);
  p.hi[m][j] = h;
  p.lo[m][j] = bf16_rne(r);
}

// ---- one split-precision GEMM pass over a 64x128 LDS tile; weights from global ----
__device__ inline void mfma_pass(
    const float* __restrict__ zbuf,
    const unsigned short* __restrict__ Whi, const unsigned short* __restrict__ Wlo,
    int rw, int m16, int quad, int lane, f32x4 acc[8])
{
  int rot = (m16 & 7) * 4;
  const float* zrow = &zbuf[(rw + m16) * 128];
#pragma unroll
  for (int kc = 0; kc < 4; ++kc) {
    int k0 = kc * 32 + quad * 8;
    float4 z0 = *(const float4*)&zrow[(k0 + rot) & 127];
    float4 z1 = *(const float4*)&zrow[(k0 + 4 + rot) & 127];
    float v[8] = {z0.x, z0.y, z0.z, z0.w, z1.x, z1.y, z1.z, z1.w};
    bf16x8 ah, al;
#pragma unroll
    for (int j = 0; j < 8; ++j) {
      unsigned short h = bf16_rne(v[j]);
      ah[j] = (short)h;
      al[j] = (short)bf16_rne(v[j] - bf16_to_f32(h));
    }
#pragma unroll
    for (int t = 0; t < 8; ++t) {
      long cb = ((t * 4 + kc) * 64 + lane) * 8;
      bf16x8 bh = *(const bf16x8*)&Whi[cb];
      bf16x8 bl = *(const bf16x8*)&Wlo[cb];
      acc[t] = __builtin_amdgcn_mfma_f32_16x16x32_bf16(ah, bh, acc[t], 0, 0, 0);
      acc[t] = __builtin_amdgcn_mfma_f32_16x16x32_bf16(ah, bl, acc[t], 0, 0, 0);
      acc[t] = __builtin_amdgcn_mfma_f32_16x16x32_bf16(al, bh, acc[t], 0, 0, 0);
    }
  }
}

// ================= fused GIN layer (layers 2,3), 64-row tile, fp16 H =================
__global__ __launch_bounds__(256, 5) void fused_gin(
    const _Float16* __restrict__ H, const int* __restrict__ rowstart,
    const int* __restrict__ eidx,
    const unsigned short* __restrict__ W1hi, const unsigned short* __restrict__ W1lo,
    const float* __restrict__ B1,
    const unsigned short* __restrict__ W2hi, const unsigned short* __restrict__ W2lo,
    const float* __restrict__ B2,
    _Float16* __restrict__ Out, int M)
{
  __shared__ float zbuf[64 * 128];   // 32 KB, rows swizzled by (r&7)*4
  int tid = threadIdx.x;
  int rbase = blockIdx.x * 64;

  // ---- phase 1: gather 64 rows (z = self + neighbor sum), fp16 rows, fp32 accum ----
  {
    int rg = tid >> 5;              // 0..7
    int c = (tid & 31) * 4;
    int pc = (c + rg * 4) & 127;
    const _Float16* Hc = H + c;
#pragma unroll 2
    for (int it = 0; it < 8; ++it) {
      int r = it * 8 + rg;
      int v = rbase + r;
      int vc = (v < M) ? v : (M - 1);
      h16x4 sv = *(const h16x4*)&Hc[(long)vc * 128];
      float4 a0 = {(float)sv[0], (float)sv[1], (float)sv[2], (float)sv[3]};
      float4 a1 = {0.f,0.f,0.f,0.f}, a2 = {0.f,0.f,0.f,0.f}, a3 = {0.f,0.f,0.f,0.f};
      int e0 = rowstart[vc], e1 = rowstart[vc + 1];
      int e = e0;
      for (; e + 4 <= e1; e += 4) {
        int s0 = eidx[e], s1 = eidx[e + 1], s2 = eidx[e + 2], s3 = eidx[e + 3];
        h16x4 h0 = *(const h16x4*)&Hc[(long)s0 * 128];
        h16x4 h1 = *(const h16x4*)&Hc[(long)s1 * 128];
        h16x4 h2 = *(const h16x4*)&Hc[(long)s2 * 128];
        h16x4 h3 = *(const h16x4*)&Hc[(long)s3 * 128];
        a0.x += (float)h0[0]; a0.y += (float)h0[1]; a0.z += (float)h0[2]; a0.w += (float)h0[3];
        a1.x += (float)h1[0]; a1.y += (float)h1[1]; a1.z += (float)h1[2]; a1.w += (float)h1[3];
        a2.x += (float)h2[0]; a2.y += (float)h2[1]; a2.z += (float)h2[2]; a2.w += (float)h2[3];
        a3.x += (float)h3[0]; a3.y += (float)h3[1]; a3.z += (float)h3[2]; a3.w += (float)h3[3];
      }
      for (; e < e1; ++e) {
        int s = eidx[e];
        h16x4 h = *(const h16x4*)&Hc[(long)s * 128];
        a1.x += (float)h[0]; a1.y += (float)h[1]; a1.z += (float)h[2]; a1.w += (float)h[3];
      }
      a0.x += a1.x + a2.x + a3.x;
      a0.y += a1.y + a2.y + a3.y;
      a0.z += a1.z + a2.z + a3.z;
      a0.w += a1.w + a2.w + a3.w;
      *(float4*)&zbuf[r * 128 + pc] = a0;
    }
  }
  __syncthreads();

  int lane = tid & 63;
  int wv = tid >> 6;
  int m16 = lane & 15;
  int quad = lane >> 4;
  int rw = wv * 16;

  // ---- phase 2: y = relu(z @ W1 + b1) ----
  f32x4 acc[8];
#pragma unroll
  for (int t = 0; t < 8; ++t) acc[t] = (f32x4){0.f, 0.f, 0.f, 0.f};
  mfma_pass(zbuf, W1hi, W1lo, rw, m16, quad, lane, acc);

  float bias[8];
#pragma unroll
  for (int t = 0; t < 8; ++t) bias[t] = B1[t * 16 + m16];

  __syncthreads();
#pragma unroll
  for (int i = 0; i < 4; ++i) {
    int r = rw + quad * 4 + i;
    int rot = (r & 7) * 4;
    float* yrow = &zbuf[r * 128];
#pragma unroll
    for (int t = 0; t < 8; ++t) {
      int col = t * 16 + m16;
      yrow[(col + rot) & 127] = fmaxf(acc[t][i] + bias[t], 0.f);
    }
  }
  __syncthreads();

  // ---- phase 3: Hout = relu(y @ W2 + b2), fp16 store ----
#pragma unroll
  for (int t = 0; t < 8; ++t) acc[t] = (f32x4){0.f, 0.f, 0.f, 0.f};
  mfma_pass(zbuf, W2hi, W2lo, rw, m16, quad, lane, acc);

#pragma unroll
  for (int t = 0; t < 8; ++t) bias[t] = B2[t * 16 + m16];

#pragma unroll
  for (int i = 0; i < 4; ++i) {
    int r = rbase + rw + quad * 4 + i;
    if (r < M) {
#pragma unroll
      for (int t = 0; t < 8; ++t) {
        float o = fmaxf(acc[t][i] + bias[t], 0.f);
        Out[(long)r * 128 + t * 16 + m16] = (_Float16)o;
      }
    }
  }
}

// ================= fused layer 1: y = relu(z1@W1+b1) in LDS; Hout(fp16) = relu(y@W2+b2) =================
__global__ __launch_bounds__(256, 5) void fused_l1(
    const float* __restrict__ Z1, const float* __restrict__ W1, const float* __restrict__ B1,
    const unsigned short* __restrict__ W2hi, const unsigned short* __restrict__ W2lo,
    const float* __restrict__ B2, _Float16* __restrict__ Out, int M)
{
  __shared__ float ybuf[64 * 128];
  int tid = threadIdx.x;
  int rbase = blockIdx.x * 64;

  {
    int c = tid & 127;
    int rh0 = (tid >> 7) * 32;
    float w1r[7];
#pragma unroll
    for (int k = 0; k < 7; ++k) w1r[k] = W1[k * 128 + c];
    float b1 = B1[c];
#pragma unroll 4
    for (int rr = 0; rr < 32; ++rr) {
      int r = rh0 + rr;
      long vc = (rbase + r < M) ? (rbase + r) : (M - 1);
      const float* zp = &Z1[vc * 7];
      float a = b1;
#pragma unroll
      for (int k = 0; k < 7; ++k) a += zp[k] * w1r[k];
      ybuf[r * 128 + ((c + (r & 7) * 4) & 127)] = fmaxf(a, 0.f);
    }
  }
  __syncthreads();

  int lane = tid & 63;
  int wv = tid >> 6;
  int m16 = lane & 15;
  int quad = lane >> 4;
  int rw = wv * 16;

  f32x4 acc[8];
#pragma unroll
  for (int t = 0; t < 8; ++t) acc[t] = (f32x4){0.f, 0.f, 0.f, 0.f};
  mfma_pass(ybuf, W2hi, W2lo, rw, m16, quad, lane, acc);

  float bias[8];
#pragma unroll
  for (int t = 0; t < 8; ++t) bias[t] = B2[t * 16 + m16];

#pragma unroll
  for (int i = 0; i < 4; ++i) {
    int r = rbase + rw + quad * 4 + i;
    if (r < M) {
#pragma unroll
      for (int t = 0; t < 8; ++t) {
        float o = fmaxf(acc[t][i] + bias[t], 0.f);
        Out[(long)r * 128 + t * 16 + m16] = (_Float16)o;
      }
    }
  }
}

// ================= fp32 GEMM for the small head (M=2048) =================
template <bool RELU>
__global__ __launch_bounds__(256) void gemm_k128(
    const float* __restrict__ Z,
    const float* __restrict__ W, const float* __restrict__ B,
    float* __restrict__ Out, int M)
{
  __shared__ float wlds[128 * 128];
  int tid = threadIdx.x;
  {
    const float4* Ws = (const float4*)W;
    float4* Wd = (float4*)wlds;
#pragma unroll
    for (int i = 0; i < 16; ++i) Wd[i * 256 + tid] = Ws[i * 256 + tid];
  }
  __syncthreads();

  int rg = tid >> 5;
  int c0 = (tid & 31) * 4;
  int rbase = blockIdx.x * 64 + rg * 8;

  int rcl[8];
#pragma unroll
  for (int i = 0; i < 8; ++i) {
    int r = rbase + i;
    rcl[i] = (r < M) ? r : (M - 1);
  }

  float acc[8][4];
#pragma unroll
  for (int i = 0; i < 8; ++i)
#pragma unroll
    for (int j = 0; j < 4; ++j) acc[i][j] = 0.f;

#pragma unroll 2
  for (int kc = 0; kc < 128; kc += 4) {
    float zv[8][4];
#pragma unroll
    for (int i = 0; i < 8; ++i) {
      float4 z = *(const float4*)&Z[(long)rcl[i] * 128 + kc];
      zv[i][0] = z.x; zv[i][1] = z.y; zv[i][2] = z.z; zv[i][3] = z.w;
    }
#pragma unroll
    for (int kk = 0; kk < 4; ++kk) {
      float4 w = *(const float4*)&wlds[(kc + kk) * 128 + c0];
#pragma unroll
      for (int i = 0; i < 8; ++i) {
        float z = zv[i][kk];
        acc[i][0] += z * w.x; acc[i][1] += z * w.y;
        acc[i][2] += z * w.z; acc[i][3] += z * w.w;
      }
    }
  }

  float4 b = *(const float4*)&B[c0];
#pragma unroll
  for (int i = 0; i < 8; ++i) {
    int r = rbase + i;
    if (r < M) {
      float4 o;
      o.x = acc[i][0] + b.x; o.y = acc[i][1] + b.y;
      o.z = acc[i][2] + b.z; o.w = acc[i][3] + b.w;
      if (RELU) {
        o.x = fmaxf(o.x, 0.f); o.y = fmaxf(o.y, 0.f);
        o.z = fmaxf(o.z, 0.f); o.w = fmaxf(o.w, 0.f);
      }
      *(float4*)&Out[(long)r * 128 + c0] = o;
    }
  }
}

// ================= pooling (fp16 H) =================
template <bool DO_CNT>
__global__ __launch_bounds__(256) void pool128(
    const _Float16* __restrict__ H, const int* __restrict__ batch,
    float* __restrict__ P, float* __restrict__ cnt, int Nn, int colOff)
{
  long t = (long)blockIdx.x * 256 + threadIdx.x;
  int cg = (int)(t & 31);
  int chunk = (int)(t >> 5);
  int i0 = chunk * 16;
  if (i0 >= Nn) return;
  int c = cg * 4;
  float4 acc = {0.f, 0.f, 0.f, 0.f};
  int curb = -1;
  float runc = 0.f;
  for (int ii = 0; ii < 16; ++ii) {
    int i = i0 + ii;
    if (i >= Nn) break;
    int b = batch[i];
    if (b != curb) {
      if (curb >= 0) {
        float* p = &P[(long)curb * 384 + colOff + c];
        atomicAdd(p + 0, acc.x); atomicAdd(p + 1, acc.y);
        atomicAdd(p + 2, acc.z); atomicAdd(p + 3, acc.w);
        if (DO_CNT && cg == 0) atomicAdd(&cnt[curb], runc);
      }
      acc.x = acc.y = acc.z = acc.w = 0.f;
      runc = 0.f;
      curb = b;
    }
    h16x4 v = *(const h16x4*)&H[(long)i * 128 + c];
    acc.x += (float)v[0]; acc.y += (float)v[1]; acc.z += (float)v[2]; acc.w += (float)v[3];
    runc += 1.f;
  }
  if (curb >= 0) {
    float* p = &P[(long)curb * 384 + colOff + c];
    atomicAdd(p + 0, acc.x); atomicAdd(p + 1, acc.y);
    atomicAdd(p + 2, acc.z); atomicAdd(p + 3, acc.w);
    if (DO_CNT && cg == 0) atomicAdd(&cnt[curb], runc);
  }
}

// ================= JK: G = P(2048x384) @ W(384x128) + cnt*B =================
__global__ __launch_bounds__(256) void jk_gemm(
    const float* __restrict__ P, const float* __restrict__ cnt,
    const float* __restrict__ W, const float* __restrict__ B,
    float* __restrict__ G)
{
  __shared__ float pl[768];
  int tid = threadIdx.x, blk = blockIdx.x;
  for (int o = tid; o < 768; o += 256) pl[o] = P[(long)blk * 768 + o];
  __syncthreads();
  int rr = tid >> 7;
  int col = tid & 127;
  int row = blk * 2 + rr;
  float acc = cnt[row] * B[col];
#pragma unroll 8
  for (int k = 0; k < 384; ++k)
    acc += pl[rr * 384 + k] * W[k * 128 + col];
  G[(long)row * 128 + col] = acc;
}

// ================= batch-norm stats =================
__global__ __launch_bounds__(256) void bn_stats(
    const float* __restrict__ ZC, const float* __restrict__ gma, const float* __restrict__ bta,
    float* __restrict__ scale, float* __restrict__ shift)
{
  int col = blockIdx.x;
  int tid = threadIdx.x;
  float s = 0.f, s2 = 0.f;
  for (int r = tid; r < NGRAPH; r += 256) {
    float v = ZC[(long)r * 128 + col];
    s += v; s2 += v * v;
  }
  for (int off = 32; off > 0; off >>= 1) {
    s += __shfl_down(s, off, 64);
    s2 += __shfl_down(s2, off, 64);
  }
  __shared__ float ls[4], ls2[4];
  int w = tid >> 6;
  if ((tid & 63) == 0) { ls[w] = s; ls2[w] = s2; }
  __syncthreads();
  if (tid == 0) {
    s = ls[0] + ls[1] + ls[2] + ls[3];
    s2 = ls2[0] + ls2[1] + ls2[2] + ls2[3];
    float mu = s * (1.f / NGRAPH);
    float var = s2 * (1.f / NGRAPH) - mu * mu;
    float rs = rsqrtf(var + 1e-5f);
    float sc = gma[col] * rs;
    scale[col] = sc;
    shift[col] = bta[col] - mu * sc;
  }
}

// ================= BN apply + relu + final [128x2] matmul =================
__global__ __launch_bounds__(256) void bn_final(
    const float* __restrict__ ZC, const float* __restrict__ scale, const float* __restrict__ shift,
    const float* __restrict__ W2, const float* __restrict__ B2, float* __restrict__ out)
{
  int g = blockIdx.x * 256 + threadIdx.x;
  if (g >= NGRAPH) return;
  float a0 = B2[0], a1 = B2[1];
#pragma unroll 4
  for (int h = 0; h < 128; ++h) {
    float zn = ZC[(long)g * 128 + h] * scale[h] + shift[h];
    zn = fmaxf(zn, 0.f);
    a0 += zn * W2[2 * h];
    a1 += zn * W2[2 * h + 1];
  }
  out[2 * g] = a0;
  out[2 * g + 1] = a1;
}

extern "C" void kernel_launch(void* const* d_in, const int* in_sizes, int n_in,
                              void* d_out, int out_size, void* d_ws, size_t ws_size,
                              hipStream_t stream)
{
  const float* x    = (const float*)d_in[0];
  const int*   ei   = (const int*)d_in[1];
  const int*   batch = (const int*)d_in[3];
  const float* g1w1 = (const float*)d_in[4];  const float* g1b1 = (const float*)d_in[5];
  const float* g1w2 = (const float*)d_in[6];  const float* g1b2 = (const float*)d_in[7];
  const float* g2w1 = (const float*)d_in[8];  const float* g2b1 = (const float*)d_in[9];
  const float* g2w2 = (const float*)d_in[10]; const float* g2b2 = (const float*)d_in[11];
  const float* g3w1 = (const float*)d_in[12]; const float* g3b1 = (const float*)d_in[13];
  const float* g3w2 = (const float*)d_in[14]; const float* g3b2 = (const float*)d_in[15];
  const float* jkw  = (const float*)d_in[16]; const float* jkb  = (const float*)d_in[17];
  const float* c1w  = (const float*)d_in[18]; const float* c1b  = (const float*)d_in[19];
  const float* bng  = (const float*)d_in[20]; const float* bnb  = (const float*)d_in[21];
  const float* c2w  = (const float*)d_in[22]; const float* c2b  = (const float*)d_in[23];

  const int N = in_sizes[3];
  const int E = in_sizes[1] / 2;
  const int* src = ei;
  const int* dst = ei + E;

  char* w = (char*)d_ws;
  auto alloc = [&](size_t bytes) {
    char* p = w;
    w += (bytes + 255) & ~(size_t)255;
    return p;
  };
  _Float16* hA = (_Float16*)alloc((size_t)N * 128 * 2);
  _Float16* hB = (_Float16*)alloc((size_t)N * 128 * 2);
  float* z1   = (float*)alloc((size_t)N * 7 * 4);
  float* P    = (float*)alloc((size_t)NGRAPH * 384 * 4);
  float* cnt  = (float*)alloc((size_t)NGRAPH * 4);
  float* gbuf = (float*)alloc((size_t)NGRAPH * 128 * 4);
  float* zc   = (float*)alloc((size_t)NGRAPH * 128 * 4);
  float* scl  = (float*)alloc(128 * 4);
  float* shf  = (float*)alloc(128 * 4);
  int* deg      = (int*)alloc((size_t)N * 4);
  int* cursor   = (int*)alloc((size_t)N * 4);
  int* rowstart = (int*)alloc((size_t)(N + 1) * 4);
  int* bsum     = (int*)alloc((size_t)1024 * 4);
  int* eidx     = (int*)alloc((size_t)E * 4);
  unsigned short* wtbuf = (unsigned short*)alloc((size_t)5 * 2 * 16384 * 2);

  unsigned short* WThi[5];
  unsigned short* WTlo[5];
  for (int m = 0; m < 5; ++m) {
    WThi[m] = wtbuf + (size_t)m * 2 * 16384;
    WTlo[m] = WThi[m] + 16384;
  }

  const int nb = (N + 255) / 256;
  const int eb = (E + 255) / 256;

  // ---- CSR build (reused by all three layers) ----
  hipMemsetAsync(deg, 0, (size_t)N * 4, stream);
  hipMemsetAsync(cursor, 0, (size_t)N * 4, stream);
  hist_deg<<<eb, 256, 0, stream>>>(dst, deg, E);
  scan1<<<nb, 256, 0, stream>>>(deg, rowstart, bsum, N);
  scan2<<<1, 1024, 0, stream>>>(bsum, nb, rowstart, N, E);
  scan3<<<nb, 256, 0, stream>>>(rowstart, bsum, N);
  fill_eidx<<<eb, 256, 0, stream>>>(src, dst, rowstart, cursor, eidx, E);

  // ---- weight prep (fragment-ordered bf16 hi/lo), one launch ----
  {
    WPs p;
    p.w[0] = g1w2; p.w[1] = g2w1; p.w[2] = g2w2; p.w[3] = g3w1; p.w[4] = g3w2;
    for (int m = 0; m < 5; ++m) { p.hi[m] = WThi[m]; p.lo[m] = WTlo[m]; }
    wprep5<<<320, 256, 0, stream>>>(p);
  }

  hipMemsetAsync(P, 0, (size_t)NGRAPH * 384 * 4, stream);
  hipMemsetAsync(cnt, 0, (size_t)NGRAPH * 4, stream);

  const int fBlocks = (N + 63) / 64;
  const int poolBlocks = (((N + 15) / 16) * 32 + 255) / 256;

  // ---- layer 1 ----
  gather7<<<(int)(((long)N * 8 + 255) / 256), 256, 0, stream>>>(x, rowstart, eidx, z1, N);
  fused_l1<<<fBlocks, 256, 0, stream>>>(z1, g1w1, g1b1, WThi[0], WTlo[0], g1b2, hA, N);
  pool128<true><<<poolBlocks, 256, 0, stream>>>(hA, batch, P, cnt, N, 0);

  // ---- layer 2 ----
  fused_gin<<<fBlocks, 256, 0, stream>>>(hA, rowstart, eidx,
      WThi[1], WTlo[1], g2b1, WThi[2], WTlo[2], g2b2, hB, N);
  pool128<false><<<poolBlocks, 256, 0, stream>>>(hB, batch, P, cnt, N, 128);

  // ---- layer 3 ----
  fused_gin<<<fBlocks, 256, 0, stream>>>(hB, rowstart, eidx,
      WThi[3], WTlo[3], g3b1, WThi[4], WTlo[4], g3b2, hA, N);
  pool128<false><<<poolBlocks, 256, 0, stream>>>(hA, batch, P, cnt, N, 256);

  // ---- head ----
  jk_gemm<<<NGRAPH / 2, 256, 0, stream>>>(P, cnt, jkw, jkb, gbuf);
  gemm_k128<false><<<(NGRAPH + 63) / 64, 256, 0, stream>>>(gbuf, c1w, c1b, zc, NGRAPH);
  bn_stats<<<128, 256, 0, stream>>>(zc, bng, bnb, scl, shf);
  bn_final<<<(NGRAPH + 255) / 256, 256, 0, stream>>>(zc, scl, shf, c2w, c2b, (float*)d_out);
}

// Round 8
// 463.764 us; speedup vs baseline: 1.2871x; 1.1297x over previous
//
#include <hip/hip_runtime.h>

#define NGRAPH 2048

typedef __attribute__((ext_vector_type(8))) short bf16x8;
typedef __attribute__((ext_vector_type(4))) float f32x4;
typedef __attribute__((ext_vector_type(8))) _Float16 h16x8;

__device__ inline unsigned short bf16_rne(float f) {
  union { float f; unsigned u; } c; c.f = f;
  unsigned u = c.u + 0x7fffu + ((c.u >> 16) & 1u);
  return (unsigned short)(u >> 16);
}
__device__ inline float bf16_to_f32(unsigned short h) {
  union { float f; unsigned u; } c; c.u = ((unsigned)h) << 16;
  return c.f;
}

// ================= CSR build =================
__global__ __launch_bounds__(256) void hist_deg(
    const int* __restrict__ dst, int* __restrict__ deg, int E)
{
  int e = blockIdx.x * 256 + threadIdx.x;
  if (e < E) atomicAdd(&deg[dst[e]], 1);
}

__global__ __launch_bounds__(256) void scan1(
    const int* __restrict__ deg, int* __restrict__ rowstart, int* __restrict__ bsum, int N)
{
  __shared__ int tmp[256];
  int i = blockIdx.x * 256 + threadIdx.x;
  int v = (i < N) ? deg[i] : 0;
  tmp[threadIdx.x] = v;
  __syncthreads();
#pragma unroll
  for (int off = 1; off < 256; off <<= 1) {
    int t = (threadIdx.x >= (unsigned)off) ? tmp[threadIdx.x - off] : 0;
    __syncthreads();
    tmp[threadIdx.x] += t;
    __syncthreads();
  }
  if (i < N) rowstart[i] = tmp[threadIdx.x] - v;
  if (threadIdx.x == 255) bsum[blockIdx.x] = tmp[255];
}

__global__ __launch_bounds__(1024) void scan2(
    int* __restrict__ bsum, int nb, int* __restrict__ rowstart, int N, int E)
{
  __shared__ int tmp[1024];
  int i = threadIdx.x;
  int v = (i < nb) ? bsum[i] : 0;
  tmp[i] = v;
  __syncthreads();
#pragma unroll
  for (int off = 1; off < 1024; off <<= 1) {
    int t = (i >= off) ? tmp[i - off] : 0;
    __syncthreads();
    tmp[i] += t;
    __syncthreads();
  }
  if (i < nb) bsum[i] = tmp[i] - v;
  if (i == 0) rowstart[N] = E;
}

__global__ __launch_bounds__(256) void scan3(
    int* __restrict__ rowstart, const int* __restrict__ bsum, int N)
{
  int i = blockIdx.x * 256 + threadIdx.x;
  if (i < N) rowstart[i] += bsum[blockIdx.x];
}

__global__ __launch_bounds__(256) void fill_eidx(
    const int* __restrict__ src, const int* __restrict__ dst,
    const int* __restrict__ rowstart, int* __restrict__ cursor,
    int* __restrict__ eidx, int E)
{
  int e = blockIdx.x * 256 + threadIdx.x;
  if (e >= E) return;
  int d = dst[e];
  int pos = rowstart[d] + atomicAdd(&cursor[d], 1);
  eidx[pos] = src[e];
}

// ================= pad x (Nx7) -> x8 (Nx8, col7 = 0) =================
__global__ __launch_bounds__(256) void pad_x(
    const float* __restrict__ x, float* __restrict__ x8, int N)
{
  int i = blockIdx.x * 256 + threadIdx.x;
  if (i >= N * 8) return;
  int v = i >> 3, j = i & 7;
  x8[i] = (j < 7) ? x[v * 7 + j] : 0.f;
}

// ================= gather7 on padded x8: 2 lanes/node, float4, 4-edge unroll =================
__global__ __launch_bounds__(256) void gather7v(
    const float* __restrict__ x8, const int* __restrict__ rowstart,
    const int* __restrict__ eidx, float* __restrict__ z1, int N)
{
  long t = (long)blockIdx.x * 256 + threadIdx.x;
  int v = (int)(t >> 1);
  if (v >= N) return;
  int c = (int)(t & 1) * 4;
  const float* Xc = x8 + c;
  float4 a0 = *(const float4*)&Xc[(long)v * 8];
  float4 a1 = {0.f, 0.f, 0.f, 0.f};
  int e0 = rowstart[v], e1 = rowstart[v + 1];
  int e = e0;
  for (; e + 4 <= e1; e += 4) {
    int s0 = eidx[e], s1 = eidx[e + 1], s2 = eidx[e + 2], s3 = eidx[e + 3];
    float4 h0 = *(const float4*)&Xc[(long)s0 * 8];
    float4 h1 = *(const float4*)&Xc[(long)s1 * 8];
    float4 h2 = *(const float4*)&Xc[(long)s2 * 8];
    float4 h3 = *(const float4*)&Xc[(long)s3 * 8];
    a0.x += h0.x + h2.x; a0.y += h0.y + h2.y; a0.z += h0.z + h2.z; a0.w += h0.w + h2.w;
    a1.x += h1.x + h3.x; a1.y += h1.y + h3.y; a1.z += h1.z + h3.z; a1.w += h1.w + h3.w;
  }
  for (; e < e1; ++e) {
    int s = eidx[e];
    float4 h = *(const float4*)&Xc[(long)s * 8];
    a1.x += h.x; a1.y += h.y; a1.z += h.z; a1.w += h.w;
  }
  a0.x += a1.x; a0.y += a1.y; a0.z += a1.z; a0.w += a1.w;
  *(float4*)&z1[(long)v * 8 + c] = a0;
}

// ================= weight prep: 5 matrices, W[k][n] f32 -> bf16 hi/lo fragment order =================
struct WPs {
  const float* w[5];
  unsigned short* hi[5];
  unsigned short* lo[5];
};
__global__ __launch_bounds__(256) void wprep5(WPs p)
{
  int g = blockIdx.x * 256 + threadIdx.x;   // 0..5*16384-1
  int m = g >> 14;
  int j = g & 16383;
  int c = j >> 3, e = j & 7;
  int t = c >> 8, kc = (c >> 6) & 3, lane = c & 63;
  int n = t * 16 + (lane & 15);
  int k = kc * 32 + (lane >> 4) * 8 + e;
  float w = p.w[m][k * 128 + n];
  unsigned short h = bf16_rne(w);
  float r = w - bf16_to_f32(h);
  p.hi[m][j] = h;
  p.lo[m][j] = bf16_rne(r);
}

// ---- split-precision GEMM pass over a 64x128 fp16 LDS tile (chunk-rot swizzle) ----
// row r chunk cidx (8 fp16) stored at chunk ((cidx + r) & 15)
__device__ inline void mfma_pass(
    const _Float16* __restrict__ zbuf,
    const unsigned short* __restrict__ Whi, const unsigned short* __restrict__ Wlo,
    int rw, int m16, int quad, int lane, f32x4 acc[8])
{
  int r = rw + m16;
  const _Float16* zrow = &zbuf[r * 128];
#pragma unroll
  for (int kc = 0; kc < 4; ++kc) {
    int cidx = kc * 4 + quad;
    h16x8 zh = *(const h16x8*)&zrow[((cidx + r) & 15) * 8];
    bf16x8 ah, al;
#pragma unroll
    for (int j = 0; j < 8; ++j) {
      float f = (float)zh[j];
      unsigned short h = bf16_rne(f);
      ah[j] = (short)h;
      al[j] = (short)bf16_rne(f - bf16_to_f32(h));
    }
#pragma unroll
    for (int t = 0; t < 8; ++t) {
      long cb = ((t * 4 + kc) * 64 + lane) * 8;
      bf16x8 bh = *(const bf16x8*)&Whi[cb];
      bf16x8 bl = *(const bf16x8*)&Wlo[cb];
      acc[t] = __builtin_amdgcn_mfma_f32_16x16x32_bf16(ah, bh, acc[t], 0, 0, 0);
      acc[t] = __builtin_amdgcn_mfma_f32_16x16x32_bf16(ah, bl, acc[t], 0, 0, 0);
      acc[t] = __builtin_amdgcn_mfma_f32_16x16x32_bf16(al, bh, acc[t], 0, 0, 0);
    }
  }
}

// ================= fused GIN layer (layers 2,3), 64-row tile, fp16 LDS, 8 blocks/CU =================
__global__ __launch_bounds__(256, 8) void fused_gin(
    const _Float16* __restrict__ H, const int* __restrict__ rowstart,
    const int* __restrict__ eidx,
    const unsigned short* __restrict__ W1hi, const unsigned short* __restrict__ W1lo,
    const float* __restrict__ B1,
    const unsigned short* __restrict__ W2hi, const unsigned short* __restrict__ W2lo,
    const float* __restrict__ B2,
    _Float16* __restrict__ Out, int M)
{
  __shared__ _Float16 zbuf[64 * 128];   // 16 KB
  int tid = threadIdx.x;
  int rbase = blockIdx.x * 64;

  // ---- phase 1: gather 64 rows; 16 lanes x 16B per row ----
  {
    int sub = tid & 15;             // chunk index 0..15 (8 fp16 each)
    int ng = tid >> 4;              // 0..15 node-groups
    const _Float16* Hc = H + sub * 8;
#pragma unroll
    for (int it = 0; it < 4; ++it) {
      int r = it * 16 + ng;
      int v = rbase + r;
      int vc = (v < M) ? v : (M - 1);
      h16x8 sv = *(const h16x8*)&Hc[(long)vc * 128];
      float a0[8], a1[8];
#pragma unroll
      for (int j = 0; j < 8; ++j) { a0[j] = (float)sv[j]; a1[j] = 0.f; }
      int e0 = rowstart[vc], e1 = rowstart[vc + 1];
      int e = e0;
      for (; e + 4 <= e1; e += 4) {
        int s0 = eidx[e], s1 = eidx[e + 1], s2 = eidx[e + 2], s3 = eidx[e + 3];
        h16x8 h0 = *(const h16x8*)&Hc[(long)s0 * 128];
        h16x8 h1 = *(const h16x8*)&Hc[(long)s1 * 128];
        h16x8 h2 = *(const h16x8*)&Hc[(long)s2 * 128];
        h16x8 h3 = *(const h16x8*)&Hc[(long)s3 * 128];
#pragma unroll
        for (int j = 0; j < 8; ++j) {
          a0[j] += (float)h0[j] + (float)h2[j];
          a1[j] += (float)h1[j] + (float)h3[j];
        }
      }
      for (; e < e1; ++e) {
        int s = eidx[e];
        h16x8 h = *(const h16x8*)&Hc[(long)s * 128];
#pragma unroll
        for (int j = 0; j < 8; ++j) a1[j] += (float)h[j];
      }
      h16x8 zo;
#pragma unroll
      for (int j = 0; j < 8; ++j) zo[j] = (_Float16)(a0[j] + a1[j]);
      *(h16x8*)&zbuf[r * 128 + ((sub + r) & 15) * 8] = zo;
    }
  }
  __syncthreads();

  int lane = tid & 63;
  int wv = tid >> 6;
  int m16 = lane & 15;
  int quad = lane >> 4;
  int rw = wv * 16;

  // ---- phase 2: y = relu(z @ W1 + b1) ----
  f32x4 acc[8];
#pragma unroll
  for (int t = 0; t < 8; ++t) acc[t] = (f32x4){0.f, 0.f, 0.f, 0.f};
  mfma_pass(zbuf, W1hi, W1lo, rw, m16, quad, lane, acc);

  float bias[8];
#pragma unroll
  for (int t = 0; t < 8; ++t) bias[t] = B1[t * 16 + m16];

  __syncthreads();
#pragma unroll
  for (int i = 0; i < 4; ++i) {
    int r = rw + quad * 4 + i;
#pragma unroll
    for (int t = 0; t < 8; ++t) {
      int col = t * 16 + m16;
      int cidx = col >> 3;
      zbuf[r * 128 + ((cidx + r) & 15) * 8 + (col & 7)] =
          (_Float16)fmaxf(acc[t][i] + bias[t], 0.f);
    }
  }
  __syncthreads();

  // ---- phase 3: Hout = relu(y @ W2 + b2), fp16 store ----
#pragma unroll
  for (int t = 0; t < 8; ++t) acc[t] = (f32x4){0.f, 0.f, 0.f, 0.f};
  mfma_pass(zbuf, W2hi, W2lo, rw, m16, quad, lane, acc);

#pragma unroll
  for (int t = 0; t < 8; ++t) bias[t] = B2[t * 16 + m16];

#pragma unroll
  for (int i = 0; i < 4; ++i) {
    int r = rbase + rw + quad * 4 + i;
    if (r < M) {
#pragma unroll
      for (int t = 0; t < 8; ++t) {
        float o = fmaxf(acc[t][i] + bias[t], 0.f);
        Out[(long)r * 128 + t * 16 + m16] = (_Float16)o;
      }
    }
  }
}

// ================= fused layer 1: y = relu(z1@W1+b1) in fp16 LDS; Hout = relu(y@W2+b2) =================
__global__ __launch_bounds__(256, 8) void fused_l1(
    const float* __restrict__ Z1, const float* __restrict__ W1, const float* __restrict__ B1,
    const unsigned short* __restrict__ W2hi, const unsigned short* __restrict__ W2lo,
    const float* __restrict__ B2, _Float16* __restrict__ Out, int M)
{
  __shared__ _Float16 ybuf[64 * 128];
  int tid = threadIdx.x;
  int rbase = blockIdx.x * 64;

  {
    int c = tid & 127;
    int cidx = c >> 3, celt = c & 7;
    int rh0 = (tid >> 7) * 32;
    float w1r[8];
#pragma unroll
    for (int k = 0; k < 7; ++k) w1r[k] = W1[k * 128 + c];
    w1r[7] = 0.f;
    float b1 = B1[c];
#pragma unroll 4
    for (int rr = 0; rr < 32; ++rr) {
      int r = rh0 + rr;
      long vc = (rbase + r < M) ? (rbase + r) : (M - 1);
      const float* zp = &Z1[vc * 8];
      float4 za = *(const float4*)zp;
      float4 zb = *(const float4*)(zp + 4);
      float a = b1 + za.x * w1r[0] + za.y * w1r[1] + za.z * w1r[2] + za.w * w1r[3]
              + zb.x * w1r[4] + zb.y * w1r[5] + zb.z * w1r[6];
      ybuf[r * 128 + ((cidx + r) & 15) * 8 + celt] = (_Float16)fmaxf(a, 0.f);
    }
  }
  __syncthreads();

  int lane = tid & 63;
  int wv = tid >> 6;
  int m16 = lane & 15;
  int quad = lane >> 4;
  int rw = wv * 16;

  f32x4 acc[8];
#pragma unroll
  for (int t = 0; t < 8; ++t) acc[t] = (f32x4){0.f, 0.f, 0.f, 0.f};
  mfma_pass(ybuf, W2hi, W2lo, rw, m16, quad, lane, acc);

  float bias[8];
#pragma unroll
  for (int t = 0; t < 8; ++t) bias[t] = B2[t * 16 + m16];

#pragma unroll
  for (int i = 0; i < 4; ++i) {
    int r = rbase + rw + quad * 4 + i;
    if (r < M) {
#pragma unroll
      for (int t = 0; t < 8; ++t) {
        float o = fmaxf(acc[t][i] + bias[t], 0.f);
        Out[(long)r * 128 + t * 16 + m16] = (_Float16)o;
      }
    }
  }
}

// ================= fp32 GEMM for the small head (M=2048) =================
template <bool RELU>
__global__ __launch_bounds__(256) void gemm_k128(
    const float* __restrict__ Z,
    const float* __restrict__ W, const float* __restrict__ B,
    float* __restrict__ Out, int M)
{
  __shared__ float wlds[128 * 128];
  int tid = threadIdx.x;
  {
    const float4* Ws = (const float4*)W;
    float4* Wd = (float4*)wlds;
#pragma unroll
    for (int i = 0; i < 16; ++i) Wd[i * 256 + tid] = Ws[i * 256 + tid];
  }
  __syncthreads();

  int rg = tid >> 5;
  int c0 = (tid & 31) * 4;
  int rbase = blockIdx.x * 64 + rg * 8;

  int rcl[8];
#pragma unroll
  for (int i = 0; i < 8; ++i) {
    int r = rbase + i;
    rcl[i] = (r < M) ? r : (M - 1);
  }

  float acc[8][4];
#pragma unroll
  for (int i = 0; i < 8; ++i)
#pragma unroll
    for (int j = 0; j < 4; ++j) acc[i][j] = 0.f;

#pragma unroll 2
  for (int kc = 0; kc < 128; kc += 4) {
    float zv[8][4];
#pragma unroll
    for (int i = 0; i < 8; ++i) {
      float4 z = *(const float4*)&Z[(long)rcl[i] * 128 + kc];
      zv[i][0] = z.x; zv[i][1] = z.y; zv[i][2] = z.z; zv[i][3] = z.w;
    }
#pragma unroll
    for (int kk = 0; kk < 4; ++kk) {
      float4 w = *(const float4*)&wlds[(kc + kk) * 128 + c0];
#pragma unroll
      for (int i = 0; i < 8; ++i) {
        float z = zv[i][kk];
        acc[i][0] += z * w.x; acc[i][1] += z * w.y;
        acc[i][2] += z * w.z; acc[i][3] += z * w.w;
      }
    }
  }

  float4 b = *(const float4*)&B[c0];
#pragma unroll
  for (int i = 0; i < 8; ++i) {
    int r = rbase + i;
    if (r < M) {
      float4 o;
      o.x = acc[i][0] + b.x; o.y = acc[i][1] + b.y;
      o.z = acc[i][2] + b.z; o.w = acc[i][3] + b.w;
      if (RELU) {
        o.x = fmaxf(o.x, 0.f); o.y = fmaxf(o.y, 0.f);
        o.z = fmaxf(o.z, 0.f); o.w = fmaxf(o.w, 0.f);
      }
      *(float4*)&Out[(long)r * 128 + c0] = o;
    }
  }
}

// ================= pooling (fp16 H) =================
typedef __attribute__((ext_vector_type(4))) _Float16 h16x4;
template <bool DO_CNT>
__global__ __launch_bounds__(256) void pool128(
    const _Float16* __restrict__ H, const int* __restrict__ batch,
    float* __restrict__ P, float* __restrict__ cnt, int Nn, int colOff)
{
  long t = (long)blockIdx.x * 256 + threadIdx.x;
  int cg = (int)(t & 31);
  int chunk = (int)(t >> 5);
  int i0 = chunk * 16;
  if (i0 >= Nn) return;
  int c = cg * 4;
  float4 acc = {0.f, 0.f, 0.f, 0.f};
  int curb = -1;
  float runc = 0.f;
  for (int ii = 0; ii < 16; ++ii) {
    int i = i0 + ii;
    if (i >= Nn) break;
    int b = batch[i];
    if (b != curb) {
      if (curb >= 0) {
        float* p = &P[(long)curb * 384 + colOff + c];
        atomicAdd(p + 0, acc.x); atomicAdd(p + 1, acc.y);
        atomicAdd(p + 2, acc.z); atomicAdd(p + 3, acc.w);
        if (DO_CNT && cg == 0) atomicAdd(&cnt[curb], runc);
      }
      acc.x = acc.y = acc.z = acc.w = 0.f;
      runc = 0.f;
      curb = b;
    }
    h16x4 v = *(const h16x4*)&H[(long)i * 128 + c];
    acc.x += (float)v[0]; acc.y += (float)v[1]; acc.z += (float)v[2]; acc.w += (float)v[3];
    runc += 1.f;
  }
  if (curb >= 0) {
    float* p = &P[(long)curb * 384 + colOff + c];
    atomicAdd(p + 0, acc.x); atomicAdd(p + 1, acc.y);
    atomicAdd(p + 2, acc.z); atomicAdd(p + 3, acc.w);
    if (DO_CNT && cg == 0) atomicAdd(&cnt[curb], runc);
  }
}

// ================= JK: G = P(2048x384) @ W(384x128) + cnt*B =================
__global__ __launch_bounds__(256) void jk_gemm(
    const float* __restrict__ P, const float* __restrict__ cnt,
    const float* __restrict__ W, const float* __restrict__ B,
    float* __restrict__ G)
{
  __shared__ float pl[768];
  int tid = threadIdx.x, blk = blockIdx.x;
  for (int o = tid; o < 768; o += 256) pl[o] = P[(long)blk * 768 + o];
  __syncthreads();
  int rr = tid >> 7;
  int col = tid & 127;
  int row = blk * 2 + rr;
  float acc = cnt[row] * B[col];
#pragma unroll 8
  for (int k = 0; k < 384; ++k)
    acc += pl[rr * 384 + k] * W[k * 128 + col];
  G[(long)row * 128 + col] = acc;
}

// ================= batch-norm stats =================
__global__ __launch_bounds__(256) void bn_stats(
    const float* __restrict__ ZC, const float* __restrict__ gma, const float* __restrict__ bta,
    float* __restrict__ scale, float* __restrict__ shift)
{
  int col = blockIdx.x;
  int tid = threadIdx.x;
  float s = 0.f, s2 = 0.f;
  for (int r = tid; r < NGRAPH; r += 256) {
    float v = ZC[(long)r * 128 + col];
    s += v; s2 += v * v;
  }
  for (int off = 32; off > 0; off >>= 1) {
    s += __shfl_down(s, off, 64);
    s2 += __shfl_down(s2, off, 64);
  }
  __shared__ float ls[4], ls2[4];
  int w = tid >> 6;
  if ((tid & 63) == 0) { ls[w] = s; ls2[w] = s2; }
  __syncthreads();
  if (tid == 0) {
    s = ls[0] + ls[1] + ls[2] + ls[3];
    s2 = ls2[0] + ls2[1] + ls2[2] + ls2[3];
    float mu = s * (1.f / NGRAPH);
    float var = s2 * (1.f / NGRAPH) - mu * mu;
    float rs = rsqrtf(var + 1e-5f);
    float sc = gma[col] * rs;
    scale[col] = sc;
    shift[col] = bta[col] - mu * sc;
  }
}

// ================= BN apply + relu + final [128x2] matmul =================
__global__ __launch_bounds__(256) void bn_final(
    const float* __restrict__ ZC, const float* __restrict__ scale, const float* __restrict__ shift,
    const float* __restrict__ W2, const float* __restrict__ B2, float* __restrict__ out)
{
  int g = blockIdx.x * 256 + threadIdx.x;
  if (g >= NGRAPH) return;
  float a0 = B2[0], a1 = B2[1];
#pragma unroll 4
  for (int h = 0; h < 128; ++h) {
    float zn = ZC[(long)g * 128 + h] * scale[h] + shift[h];
    zn = fmaxf(zn, 0.f);
    a0 += zn * W2[2 * h];
    a1 += zn * W2[2 * h + 1];
  }
  out[2 * g] = a0;
  out[2 * g + 1] = a1;
}

extern "C" void kernel_launch(void* const* d_in, const int* in_sizes, int n_in,
                              void* d_out, int out_size, void* d_ws, size_t ws_size,
                              hipStream_t stream)
{
  const float* x    = (const float*)d_in[0];
  const int*   ei   = (const int*)d_in[1];
  const int*   batch = (const int*)d_in[3];
  const float* g1w1 = (const float*)d_in[4];  const float* g1b1 = (const float*)d_in[5];
  const float* g1w2 = (const float*)d_in[6];  const float* g1b2 = (const float*)d_in[7];
  const float* g2w1 = (const float*)d_in[8];  const float* g2b1 = (const float*)d_in[9];
  const float* g2w2 = (const float*)d_in[10]; const float* g2b2 = (const float*)d_in[11];
  const float* g3w1 = (const float*)d_in[12]; const float* g3b1 = (const float*)d_in[13];
  const float* g3w2 = (const float*)d_in[14]; const float* g3b2 = (const float*)d_in[15];
  const float* jkw  = (const float*)d_in[16]; const float* jkb  = (const float*)d_in[17];
  const float* c1w  = (const float*)d_in[18]; const float* c1b  = (const float*)d_in[19];
  const float* bng  = (const float*)d_in[20]; const float* bnb  = (const float*)d_in[21];
  const float* c2w  = (const float*)d_in[22]; const float* c2b  = (const float*)d_in[23];

  const int N = in_sizes[3];
  const int E = in_sizes[1] / 2;
  const int* src = ei;
  const int* dst = ei + E;

  char* w = (char*)d_ws;
  auto alloc = [&](size_t bytes) {
    char* p = w;
    w += (bytes + 255) & ~(size_t)255;
    return p;
  };
  _Float16* hA = (_Float16*)alloc((size_t)N * 128 * 2);
  _Float16* hB = (_Float16*)alloc((size_t)N * 128 * 2);
  float* x8   = (float*)alloc((size_t)N * 8 * 4);
  float* z1   = (float*)alloc((size_t)N * 8 * 4);
  float* P    = (float*)alloc((size_t)NGRAPH * 384 * 4);   // P and cnt contiguous: one memset
  float* cnt  = (float*)alloc((size_t)NGRAPH * 4);
  float* gbuf = (float*)alloc((size_t)NGRAPH * 128 * 4);
  float* zc   = (float*)alloc((size_t)NGRAPH * 128 * 4);
  float* scl  = (float*)alloc(128 * 4);
  float* shf  = (float*)alloc(128 * 4);
  int* deg      = (int*)alloc((size_t)N * 4);              // deg and cursor contiguous
  int* cursor   = (int*)alloc((size_t)N * 4);
  int* rowstart = (int*)alloc((size_t)(N + 1) * 4);
  int* bsum     = (int*)alloc((size_t)1024 * 4);
  int* eidx     = (int*)alloc((size_t)E * 4);
  unsigned short* wtbuf = (unsigned short*)alloc((size_t)5 * 2 * 16384 * 2);

  unsigned short* WThi[5];
  unsigned short* WTlo[5];
  for (int m = 0; m < 5; ++m) {
    WThi[m] = wtbuf + (size_t)m * 2 * 16384;
    WTlo[m] = WThi[m] + 16384;
  }

  const int nb = (N + 255) / 256;
  const int eb = (E + 255) / 256;
  const size_t npad = ((size_t)N * 4 + 255) & ~(size_t)255;

  // ---- CSR build (deg+cursor zeroed in one memset) ----
  hipMemsetAsync(deg, 0, npad + (size_t)N * 4, stream);
  hist_deg<<<eb, 256, 0, stream>>>(dst, deg, E);
  scan1<<<nb, 256, 0, stream>>>(deg, rowstart, bsum, N);
  scan2<<<1, 1024, 0, stream>>>(bsum, nb, rowstart, N, E);
  scan3<<<nb, 256, 0, stream>>>(rowstart, bsum, N);
  fill_eidx<<<eb, 256, 0, stream>>>(src, dst, rowstart, cursor, eidx, E);

  // ---- weight prep + x pad ----
  {
    WPs p;
    p.w[0] = g1w2; p.w[1] = g2w1; p.w[2] = g2w2; p.w[3] = g3w1; p.w[4] = g3w2;
    for (int m = 0; m < 5; ++m) { p.hi[m] = WThi[m]; p.lo[m] = WTlo[m]; }
    wprep5<<<320, 256, 0, stream>>>(p);
  }
  pad_x<<<(N * 8 + 255) / 256, 256, 0, stream>>>(x, x8, N);

  // P + cnt zeroed in one memset (contiguous, P size is 256B-aligned)
  hipMemsetAsync(P, 0, (size_t)NGRAPH * 384 * 4 + (size_t)NGRAPH * 4, stream);

  const int fBlocks = (N + 63) / 64;
  const int poolBlocks = (((N + 15) / 16) * 32 + 255) / 256;

  // ---- layer 1 ----
  gather7v<<<(N * 2 + 255) / 256, 256, 0, stream>>>(x8, rowstart, eidx, z1, N);
  fused_l1<<<fBlocks, 256, 0, stream>>>(z1, g1w1, g1b1, WThi[0], WTlo[0], g1b2, hA, N);
  pool128<true><<<poolBlocks, 256, 0, stream>>>(hA, batch, P, cnt, N, 0);

  // ---- layer 2 ----
  fused_gin<<<fBlocks, 256, 0, stream>>>(hA, rowstart, eidx,
      WThi[1], WTlo[1], g2b1, WThi[2], WTlo[2], g2b2, hB, N);
  pool128<false><<<poolBlocks, 256, 0, stream>>>(hB, batch, P, cnt, N, 128);

  // ---- layer 3 ----
  fused_gin<<<fBlocks, 256, 0, stream>>>(hB, rowstart, eidx,
      WThi[3], WTlo[3], g3b1, WThi[4], WTlo[4], g3b2, hA, N);
  pool128<false><<<poolBlocks, 256, 0, stream>>>(hA, batch, P, cnt, N, 256);

  // ---- head ----
  jk_gemm<<<NGRAPH / 2, 256, 0, stream>>>(P, cnt, jkw, jkb, gbuf);
  gemm_k128<false><<<(NGRAPH + 63) / 64, 256, 0, stream>>>(gbuf, c1w, c1b, zc, NGRAPH);
  bn_stats<<<128, 256, 0, stream>>>(zc, bng, bnb, scl, shf);
  bn_final<<<(NGRAPH + 255) / 256, 256, 0, stream>>>(zc, scl, shf, c2w, c2b, (float*)d_out);
}